// Round 1
// baseline (3182.857 us; speedup 1.0000x reference)
//
#include <hip/hip_runtime.h>
#include <cmath>

// LeWin block: B=8, C=64, H=W=256, ws=8, heads=4, hd=16, hidden=256.
// Kernel A: LN1 + window attention + proj + residual  -> x1 (B,H,W,C) in ws
// Kernel B: LN2 + FFN + depthwise conv + adds -> out (B,C,H,W)

__device__ __forceinline__ void fma4(float a, const float* __restrict__ w, float acc[4]) {
  const float4 u = *(const float4*)(w);
  acc[0] += a * u.x; acc[1] += a * u.y; acc[2] += a * u.z; acc[3] += a * u.w;
}

__device__ __forceinline__ void fma16(float a, const float* __restrict__ w, float acc[16]) {
  const float4 u0 = *(const float4*)(w);
  const float4 u1 = *(const float4*)(w + 4);
  const float4 u2 = *(const float4*)(w + 8);
  const float4 u3 = *(const float4*)(w + 12);
  acc[0]  += a * u0.x; acc[1]  += a * u0.y; acc[2]  += a * u0.z; acc[3]  += a * u0.w;
  acc[4]  += a * u1.x; acc[5]  += a * u1.y; acc[6]  += a * u1.z; acc[7]  += a * u1.w;
  acc[8]  += a * u2.x; acc[9]  += a * u2.y; acc[10] += a * u2.z; acc[11] += a * u2.w;
  acc[12] += a * u3.x; acc[13] += a * u3.y; acc[14] += a * u3.z; acc[15] += a * u3.w;
}

__global__ __launch_bounds__(256, 2)
void win_attn_kernel(const float* __restrict__ x,
                     const float* __restrict__ qkv_w,
                     const float* __restrict__ qkv_b,
                     const float* __restrict__ proj_w,
                     const float* __restrict__ proj_b,
                     const float* __restrict__ rpb,
                     const float* __restrict__ n1g,
                     const float* __restrict__ n1b,
                     float* __restrict__ x1)
{
  __shared__ float xw[64][65];   // raw window, token-major
  __shared__ float xn[64][65];   // LN1 output; reused as x1 staging at end
  __shared__ float qh[64][17];
  __shared__ float kh[64][17];
  __shared__ float vh[64][17];
  __shared__ float sc[64][65];   // scores / softmax
  __shared__ float ot[64][65];   // attention output (pre-proj)

  const int tid = threadIdx.x;
  const int wid = blockIdx.x;
  const int b  = wid >> 10;
  const int wy = (wid >> 5) & 31;
  const int wx = wid & 31;
  const int y0 = wy << 3, x0 = wx << 3;

  // ---- load + transpose (B,C,H,W) -> xw[token][channel] ----
  const size_t imgbase = (size_t)b * 64 * 65536;
#pragma unroll
  for (int i = 0; i < 16; ++i) {
    int idx = i * 256 + tid;
    int c = idx >> 6, t = idx & 63;        // c uniform per wave, t per-lane
    int ty = t >> 3, tx = t & 7;
    xw[t][c] = x[imgbase + ((size_t)c << 16) + (size_t)(y0 + ty) * 256 + (x0 + tx)];
  }
  __syncthreads();

  // ---- LayerNorm1 (4 lanes per token) ----
  {
    const int t = tid >> 2, q = tid & 3;
    float xv[16], s = 0.f, s2 = 0.f;
#pragma unroll
    for (int i = 0; i < 16; ++i) { float v = xw[t][q*16 + i]; xv[i] = v; s += v; s2 += v*v; }
    s  += __shfl_xor(s, 1);  s  += __shfl_xor(s, 2);
    s2 += __shfl_xor(s2, 1); s2 += __shfl_xor(s2, 2);
    const float mu   = s * 0.015625f;
    const float rstd = rsqrtf(s2 * 0.015625f - mu*mu + 1e-5f);
#pragma unroll
    for (int i = 0; i < 16; ++i) {
      int c = q*16 + i;
      xn[t][c] = (xv[i] - mu) * rstd * n1g[c] + n1b[c];
    }
  }
  __syncthreads();

  const int lane = tid & 63;
  const int g    = tid >> 6;           // wave id 0..3
  const int ty_i = lane >> 3, tx_i = lane & 7;

  for (int h = 0; h < 4; ++h) {
    // ---- QKV for head h: wave g computes d = g*4..g*4+3 for q,k,v ----
    {
      float aq[4] = {0,0,0,0}, ak[4] = {0,0,0,0}, avv[4] = {0,0,0,0};
      const float* wq = qkv_w +   0 + h*16 + g*4;
      const float* wk = qkv_w +  64 + h*16 + g*4;
      const float* wv = qkv_w + 128 + h*16 + g*4;
#pragma unroll 4
      for (int cc = 0; cc < 64; ++cc) {
        const float xv = xn[lane][cc];
        fma4(xv, wq + cc*192, aq);
        fma4(xv, wk + cc*192, ak);
        fma4(xv, wv + cc*192, avv);
      }
#pragma unroll
      for (int d = 0; d < 4; ++d) {
        qh[lane][g*4 + d] = (aq[d]  + qkv_b[  0 + h*16 + g*4 + d]) * 0.25f; // scale = hd^-0.5
        kh[lane][g*4 + d] =  ak[d]  + qkv_b[ 64 + h*16 + g*4 + d];
        vh[lane][g*4 + d] =  avv[d] + qkv_b[128 + h*16 + g*4 + d];
      }
    }
    __syncthreads();

    // ---- scores = q.kT + rel-pos bias (wave g: cols g*16..g*16+15) ----
    {
      float qreg[16];
#pragma unroll
      for (int d = 0; d < 16; ++d) qreg[d] = qh[lane][d];
#pragma unroll
      for (int jj = 0; jj < 16; ++jj) {
        const int j = g*16 + jj;
        const int ty_j = j >> 3, tx_j = j & 7;
        const int ridx = (ty_i - ty_j + 7)*15 + (tx_i - tx_j + 7);
        float acc = rpb[ridx*4 + h];
#pragma unroll
        for (int d = 0; d < 16; ++d) acc += qreg[d] * kh[j][d];
        sc[lane][j] = acc;
      }
    }
    __syncthreads();

    // ---- softmax per row (4 lanes per row) ----
    {
      const int t = tid >> 2, q = tid & 3;
      float pv[16], m = -1e30f;
#pragma unroll
      for (int i = 0; i < 16; ++i) { pv[i] = sc[t][q*16 + i]; m = fmaxf(m, pv[i]); }
      m = fmaxf(m, __shfl_xor(m, 1)); m = fmaxf(m, __shfl_xor(m, 2));
      float ssum = 0.f;
#pragma unroll
      for (int i = 0; i < 16; ++i) { pv[i] = __expf(pv[i] - m); ssum += pv[i]; }
      ssum += __shfl_xor(ssum, 1); ssum += __shfl_xor(ssum, 2);
      const float r = 1.f / ssum;
#pragma unroll
      for (int i = 0; i < 16; ++i) sc[t][q*16 + i] = pv[i] * r;
    }
    __syncthreads();

    // ---- out_h = softmax @ v (wave g: d = g*4..g*4+3) ----
    {
      float a[4] = {0,0,0,0};
#pragma unroll 8
      for (int j = 0; j < 64; ++j) {
        const float s_ = sc[lane][j];
        a[0] += s_ * vh[j][g*4 + 0];
        a[1] += s_ * vh[j][g*4 + 1];
        a[2] += s_ * vh[j][g*4 + 2];
        a[3] += s_ * vh[j][g*4 + 3];
      }
#pragma unroll
      for (int d = 0; d < 4; ++d) ot[lane][h*16 + g*4 + d] = a[d];
    }
    __syncthreads();
  }

  // ---- proj + residual: wave g computes c' = g*16..g*16+15 ----
  {
    float acc[16];
#pragma unroll
    for (int m = 0; m < 16; ++m) acc[m] = proj_b[g*16 + m];
    const float* pw = proj_w + g*16;
#pragma unroll 4
    for (int cc = 0; cc < 64; ++cc)
      fma16(ot[lane][cc], pw + cc*64, acc);
#pragma unroll
    for (int m = 0; m < 16; ++m)
      xn[lane][g*16 + m] = acc[m] + xw[lane][g*16 + m];   // reuse xn as staging
  }
  __syncthreads();

  // ---- write x1 (B,H,W,C), channel-contiguous coalesced ----
#pragma unroll
  for (int i = 0; i < 16; ++i) {
    int idx = i * 256 + tid;
    int t = idx >> 6, c = idx & 63;        // c per-lane contiguous
    int ty = t >> 3, tx = t & 7;
    x1[(((size_t)b*256 + (y0 + ty))*256 + (x0 + tx))*64 + c] = xn[t][c];
  }
}

__global__ __launch_bounds__(256, 2)
void ffn_conv_kernel(const float* __restrict__ x1,
                     const float* __restrict__ n2g, const float* __restrict__ n2b,
                     const float* __restrict__ w1,  const float* __restrict__ b1,
                     const float* __restrict__ w2,  const float* __restrict__ b2,
                     const float* __restrict__ dww, const float* __restrict__ dwb,
                     float* __restrict__ out)
{
  __shared__ float x1t[64][100];  // channel-major 10x10 halo tile
  __shared__ float xn[64][65];    // LN2 output, token-major
  __shared__ float ob[64][65];    // x1 + conv + ffn accumulator
  __shared__ float hid[64][66];   // hidden quarter staging

  const int tid = threadIdx.x;
  const int wid = blockIdx.x;
  const int b  = wid >> 10;
  const int wy = (wid >> 5) & 31;
  const int wx = wid & 31;
  const int y0 = wy << 3, x0 = wx << 3;

  // ---- halo load (zero pad at image edges) ----
#pragma unroll
  for (int i = 0; i < 25; ++i) {
    int idx = i * 256 + tid;               // 6400 = 64ch * 100pix
    int p = idx >> 6, c = idx & 63;        // p uniform per wave, c per-lane
    int hy = p / 10, hx = p - hy*10;
    int gy = y0 + hy - 1, gx = x0 + hx - 1;
    float v = 0.f;
    if ((unsigned)gy < 256u && (unsigned)gx < 256u)
      v = x1[(((size_t)b*256 + gy)*256 + gx)*64 + c];
    x1t[c][p] = v;
  }
  __syncthreads();

  const int lane = tid & 63;
  const int g    = tid >> 6;
  const int cty = lane >> 3, ctx = lane & 7;
  const int cp  = (cty + 1)*10 + ctx + 1;

  // ---- LayerNorm2 ----
  {
    const int t = tid >> 2, q = tid & 3;
    const int pp = ((t >> 3) + 1)*10 + (t & 7) + 1;
    float xv[16], s = 0.f, s2 = 0.f;
#pragma unroll
    for (int i = 0; i < 16; ++i) { float v = x1t[q*16 + i][pp]; xv[i] = v; s += v; s2 += v*v; }
    s  += __shfl_xor(s, 1);  s  += __shfl_xor(s, 2);
    s2 += __shfl_xor(s2, 1); s2 += __shfl_xor(s2, 2);
    const float mu   = s * 0.015625f;
    const float rstd = rsqrtf(s2 * 0.015625f - mu*mu + 1e-5f);
#pragma unroll
    for (int i = 0; i < 16; ++i) {
      int c = q*16 + i;
      xn[t][c] = (xv[i] - mu) * rstd * n2g[c] + n2b[c];
    }
  }
  __syncthreads();

  // ---- depthwise 3x3 conv + x1 -> ob (wave g owns channels g*16..g*16+15) ----
  {
#pragma unroll
    for (int i = 0; i < 16; ++i) {
      const int c = g*16 + i;
      const float* wc = dww + c*9;
      float acc = dwb[c];
#pragma unroll
      for (int dy = 0; dy < 3; ++dy)
#pragma unroll
        for (int dx = 0; dx < 3; ++dx)
          acc += wc[dy*3 + dx] * x1t[c][(cty + dy)*10 + (ctx + dx)];
      ob[lane][c] = x1t[c][cp] + acc;
    }
  }

  // ---- FFN: hidden processed in 4 quarters of 64 through LDS ----
  float acc2[16];
#pragma unroll
  for (int m = 0; m < 16; ++m) acc2[m] = b2[g*16 + m];

  for (int qtr = 0; qtr < 4; ++qtr) {
    float a1[16];
#pragma unroll
    for (int m = 0; m < 16; ++m) a1[m] = b1[qtr*64 + g*16 + m];
    const float* w1p = w1 + qtr*64 + g*16;
#pragma unroll 4
    for (int cc = 0; cc < 64; ++cc)
      fma16(xn[lane][cc], w1p + cc*256, a1);
#pragma unroll
    for (int m = 0; m < 16; ++m) {
      float hv = a1[m];
      hv = 0.5f * hv * (1.f + erff(hv * 0.70710678118654752f));  // exact GELU
      hid[lane][g*16 + m] = hv;
    }
    __syncthreads();
    const float* w2p = w2 + qtr*64*64 + g*16;
#pragma unroll 4
    for (int hh = 0; hh < 64; ++hh)
      fma16(hid[lane][hh], w2p + hh*64, acc2);
    __syncthreads();
  }
#pragma unroll
  for (int m = 0; m < 16; ++m) ob[lane][g*16 + m] += acc2[m];
  __syncthreads();

  // ---- write out (B,C,H,W) ----
#pragma unroll
  for (int i = 0; i < 16; ++i) {
    int idx = i * 256 + tid;
    int c = idx >> 6, t = idx & 63;        // t per-lane -> tx contiguous
    int ty = t >> 3, tx = t & 7;
    out[(((size_t)b*64 + c)*256 + (y0 + ty))*256 + (x0 + tx)] = ob[t][c];
  }
}

extern "C" void kernel_launch(void* const* d_in, const int* in_sizes, int n_in,
                              void* d_out, int out_size, void* d_ws, size_t ws_size,
                              hipStream_t stream) {
  const float* x      = (const float*)d_in[0];
  const float* qkv_w  = (const float*)d_in[1];
  const float* qkv_b  = (const float*)d_in[2];
  const float* proj_w = (const float*)d_in[3];
  const float* proj_b = (const float*)d_in[4];
  const float* rpb    = (const float*)d_in[5];
  const float* n1g    = (const float*)d_in[6];
  const float* n1b    = (const float*)d_in[7];
  const float* n2g    = (const float*)d_in[8];
  const float* n2b    = (const float*)d_in[9];
  const float* w1     = (const float*)d_in[10];
  const float* b1     = (const float*)d_in[11];
  const float* w2     = (const float*)d_in[12];
  const float* b2     = (const float*)d_in[13];
  const float* dww    = (const float*)d_in[14];
  const float* dwb    = (const float*)d_in[15];
  float* out = (float*)d_out;
  float* x1  = (float*)d_ws;   // 8*256*256*64 floats = 128 MiB

  win_attn_kernel<<<8192, 256, 0, stream>>>(x, qkv_w, qkv_b, proj_w, proj_b,
                                            rpb, n1g, n1b, x1);
  ffn_conv_kernel<<<8192, 256, 0, stream>>>(x1, n2g, n2b, w1, b1, w2, b2,
                                            dww, dwb, out);
}

// Round 2
// 1486.728 us; speedup vs baseline: 2.1408x; 2.1408x over previous
//
#include <hip/hip_runtime.h>
#include <cmath>

// LeWin block: B=8, C=64, H=W=256, ws=8, heads=4, hd=16, hidden=256.
// Kernel A: LN1 + window attention + proj + residual  -> x1 (B,H,W,C) in ws
// Kernel B: LN2 + FFN (bf16 MFMA) + depthwise conv + adds -> out (B,C,H,W)

typedef __attribute__((ext_vector_type(8))) short bf16x8;
typedef __attribute__((ext_vector_type(4))) float f32x4;

static __device__ __forceinline__ unsigned short f2bf(float f) {
  union { float f; unsigned u; } v; v.f = f;
  unsigned r = v.u + 0x7FFF + ((v.u >> 16) & 1);   // round-to-nearest-even
  return (unsigned short)(r >> 16);
}
static __device__ __forceinline__ float bf2f(unsigned short u) {
  union { unsigned u; float f; } v; v.u = ((unsigned)u) << 16;
  return v.f;
}

__device__ __forceinline__ void fma4(float a, const float* __restrict__ w, float acc[4]) {
  const float4 u = *(const float4*)(w);
  acc[0] += a * u.x; acc[1] += a * u.y; acc[2] += a * u.z; acc[3] += a * u.w;
}

__device__ __forceinline__ void fma16(float a, const float* __restrict__ w, float acc[16]) {
  const float4 u0 = *(const float4*)(w);
  const float4 u1 = *(const float4*)(w + 4);
  const float4 u2 = *(const float4*)(w + 8);
  const float4 u3 = *(const float4*)(w + 12);
  acc[0]  += a * u0.x; acc[1]  += a * u0.y; acc[2]  += a * u0.z; acc[3]  += a * u0.w;
  acc[4]  += a * u1.x; acc[5]  += a * u1.y; acc[6]  += a * u1.z; acc[7]  += a * u1.w;
  acc[8]  += a * u2.x; acc[9]  += a * u2.y; acc[10] += a * u2.z; acc[11] += a * u2.w;
  acc[12] += a * u3.x; acc[13] += a * u3.y; acc[14] += a * u3.z; acc[15] += a * u3.w;
}

// ==================== Kernel A: window attention (unchanged) ====================
__global__ __launch_bounds__(256, 2)
void win_attn_kernel(const float* __restrict__ x,
                     const float* __restrict__ qkv_w,
                     const float* __restrict__ qkv_b,
                     const float* __restrict__ proj_w,
                     const float* __restrict__ proj_b,
                     const float* __restrict__ rpb,
                     const float* __restrict__ n1g,
                     const float* __restrict__ n1b,
                     float* __restrict__ x1)
{
  __shared__ float xw[64][65];
  __shared__ float xn[64][65];
  __shared__ float qh[64][17];
  __shared__ float kh[64][17];
  __shared__ float vh[64][17];
  __shared__ float sc[64][65];
  __shared__ float ot[64][65];

  const int tid = threadIdx.x;
  const int wid = blockIdx.x;
  const int b  = wid >> 10;
  const int wy = (wid >> 5) & 31;
  const int wx = wid & 31;
  const int y0 = wy << 3, x0 = wx << 3;

  const size_t imgbase = (size_t)b * 64 * 65536;
#pragma unroll
  for (int i = 0; i < 16; ++i) {
    int idx = i * 256 + tid;
    int c = idx >> 6, t = idx & 63;
    int ty = t >> 3, tx = t & 7;
    xw[t][c] = x[imgbase + ((size_t)c << 16) + (size_t)(y0 + ty) * 256 + (x0 + tx)];
  }
  __syncthreads();

  {
    const int t = tid >> 2, q = tid & 3;
    float xv[16], s = 0.f, s2 = 0.f;
#pragma unroll
    for (int i = 0; i < 16; ++i) { float v = xw[t][q*16 + i]; xv[i] = v; s += v; s2 += v*v; }
    s  += __shfl_xor(s, 1);  s  += __shfl_xor(s, 2);
    s2 += __shfl_xor(s2, 1); s2 += __shfl_xor(s2, 2);
    const float mu   = s * 0.015625f;
    const float rstd = rsqrtf(s2 * 0.015625f - mu*mu + 1e-5f);
#pragma unroll
    for (int i = 0; i < 16; ++i) {
      int c = q*16 + i;
      xn[t][c] = (xv[i] - mu) * rstd * n1g[c] + n1b[c];
    }
  }
  __syncthreads();

  const int lane = tid & 63;
  const int g    = tid >> 6;
  const int ty_i = lane >> 3, tx_i = lane & 7;

  for (int h = 0; h < 4; ++h) {
    {
      float aq[4] = {0,0,0,0}, ak[4] = {0,0,0,0}, avv[4] = {0,0,0,0};
      const float* wq = qkv_w +   0 + h*16 + g*4;
      const float* wk = qkv_w +  64 + h*16 + g*4;
      const float* wv = qkv_w + 128 + h*16 + g*4;
#pragma unroll 4
      for (int cc = 0; cc < 64; ++cc) {
        const float xv = xn[lane][cc];
        fma4(xv, wq + cc*192, aq);
        fma4(xv, wk + cc*192, ak);
        fma4(xv, wv + cc*192, avv);
      }
#pragma unroll
      for (int d = 0; d < 4; ++d) {
        qh[lane][g*4 + d] = (aq[d]  + qkv_b[  0 + h*16 + g*4 + d]) * 0.25f;
        kh[lane][g*4 + d] =  ak[d]  + qkv_b[ 64 + h*16 + g*4 + d];
        vh[lane][g*4 + d] =  avv[d] + qkv_b[128 + h*16 + g*4 + d];
      }
    }
    __syncthreads();

    {
      float qreg[16];
#pragma unroll
      for (int d = 0; d < 16; ++d) qreg[d] = qh[lane][d];
#pragma unroll
      for (int jj = 0; jj < 16; ++jj) {
        const int j = g*16 + jj;
        const int ty_j = j >> 3, tx_j = j & 7;
        const int ridx = (ty_i - ty_j + 7)*15 + (tx_i - tx_j + 7);
        float acc = rpb[ridx*4 + h];
#pragma unroll
        for (int d = 0; d < 16; ++d) acc += qreg[d] * kh[j][d];
        sc[lane][j] = acc;
      }
    }
    __syncthreads();

    {
      const int t = tid >> 2, q = tid & 3;
      float pv[16], m = -1e30f;
#pragma unroll
      for (int i = 0; i < 16; ++i) { pv[i] = sc[t][q*16 + i]; m = fmaxf(m, pv[i]); }
      m = fmaxf(m, __shfl_xor(m, 1)); m = fmaxf(m, __shfl_xor(m, 2));
      float ssum = 0.f;
#pragma unroll
      for (int i = 0; i < 16; ++i) { pv[i] = __expf(pv[i] - m); ssum += pv[i]; }
      ssum += __shfl_xor(ssum, 1); ssum += __shfl_xor(ssum, 2);
      const float r = 1.f / ssum;
#pragma unroll
      for (int i = 0; i < 16; ++i) sc[t][q*16 + i] = pv[i] * r;
    }
    __syncthreads();

    {
      float a[4] = {0,0,0,0};
#pragma unroll 8
      for (int j = 0; j < 64; ++j) {
        const float s_ = sc[lane][j];
        a[0] += s_ * vh[j][g*4 + 0];
        a[1] += s_ * vh[j][g*4 + 1];
        a[2] += s_ * vh[j][g*4 + 2];
        a[3] += s_ * vh[j][g*4 + 3];
      }
#pragma unroll
      for (int d = 0; d < 4; ++d) ot[lane][h*16 + g*4 + d] = a[d];
    }
    __syncthreads();
  }

  {
    float acc[16];
#pragma unroll
    for (int m = 0; m < 16; ++m) acc[m] = proj_b[g*16 + m];
    const float* pw = proj_w + g*16;
#pragma unroll 4
    for (int cc = 0; cc < 64; ++cc)
      fma16(ot[lane][cc], pw + cc*64, acc);
#pragma unroll
    for (int m = 0; m < 16; ++m)
      xn[lane][g*16 + m] = acc[m] + xw[lane][g*16 + m];
  }
  __syncthreads();

#pragma unroll
  for (int i = 0; i < 16; ++i) {
    int idx = i * 256 + tid;
    int t = idx >> 6, c = idx & 63;
    int ty = t >> 3, tx = t & 7;
    x1[(((size_t)b*256 + (y0 + ty))*256 + (x0 + tx))*64 + c] = xn[t][c];
  }
}

// ==================== Kernel B: LN2 + MFMA FFN + dwconv ====================
// LDS pitches: all 16B-aligned rows, even bank spread.
#define HLP 66    // halo pitch (bf16), pixel-major [100][HLP]
#define OBP 68    // ob pitch (f32)
#define XNP 72    // xn pitch (bf16)
#define HP  264   // hid pitch (bf16)

__global__ __launch_bounds__(256, 2)
void ffn_conv_kernel(const float* __restrict__ x1,
                     const float* __restrict__ n2g, const float* __restrict__ n2b,
                     const float* __restrict__ w1,  const float* __restrict__ b1,
                     const float* __restrict__ w2,  const float* __restrict__ b2,
                     const float* __restrict__ dww, const float* __restrict__ dwb,
                     float* __restrict__ out)
{
  __shared__ unsigned short x1h[100][HLP];  // bf16 halo, pixel-major
  __shared__ float          ob[64][OBP];    // residual + conv + ffn accumulator
  __shared__ unsigned short xn[64][XNP];    // LN2 output bf16
  __shared__ unsigned short hid[64][HP];    // hidden bf16 (64 tok x 256)

  const int tid = threadIdx.x;
  const int wid = blockIdx.x;
  const int b  = wid >> 10;
  const int wy = (wid >> 5) & 31;
  const int wx = wid & 31;
  const int y0 = wy << 3, x0 = wx << 3;

  // ---- halo load (100 px x 64 ch), fp32 -> bf16, pixel-major ----
#pragma unroll
  for (int i = 0; i < 13; ++i) {
    int u = i * 256 + tid;                 // 3200 float2 units
    if (u < 3200) {
      int p = u >> 5, c2 = (u & 31) << 1;
      int py = p / 10, px = p - py*10;
      int gy = y0 + py - 1, gx = x0 + px - 1;
      float vx = 0.f, vy = 0.f;
      if ((unsigned)gy < 256u && (unsigned)gx < 256u) {
        const float2 v = *(const float2*)&x1[(((size_t)b*256 + gy)*256 + gx)*64 + c2];
        vx = v.x; vy = v.y;
      }
      unsigned pk = (unsigned)f2bf(vx) | ((unsigned)f2bf(vy) << 16);
      *(unsigned*)&x1h[p][c2] = pk;
    }
  }

  // ---- residual init: ob[t][c] = x1 window (fp32, coalesced float4) ----
#pragma unroll
  for (int i = 0; i < 4; ++i) {
    int u = i * 256 + tid;                 // 1024 float4 units
    int t = u >> 4, c4 = (u & 15) << 2;
    int ty = t >> 3, tx = t & 7;
    const float4 v = *(const float4*)&x1[(((size_t)b*256 + y0 + ty)*256 + x0 + tx)*64 + c4];
    *(float4*)&ob[t][c4] = v;
  }
  __syncthreads();

  const int lane = tid & 63;
  const int g    = tid >> 6;     // wave 0..3
  const int lr   = lane & 15;
  const int lg   = lane >> 4;

  // ---- LayerNorm2 (4 lanes per token), write xn bf16 ----
  {
    const int t = tid >> 2, q = tid & 3;
    float xv[16], s = 0.f, s2 = 0.f;
#pragma unroll
    for (int i = 0; i < 4; ++i) {
      const float4 v = *(const float4*)&ob[t][q*16 + i*4];
      xv[i*4+0] = v.x; xv[i*4+1] = v.y; xv[i*4+2] = v.z; xv[i*4+3] = v.w;
      s += v.x + v.y + v.z + v.w;
      s2 += v.x*v.x + v.y*v.y + v.z*v.z + v.w*v.w;
    }
    s  += __shfl_xor(s, 1);  s  += __shfl_xor(s, 2);
    s2 += __shfl_xor(s2, 1); s2 += __shfl_xor(s2, 2);
    const float mu   = s * 0.015625f;
    const float rstd = rsqrtf(s2 * 0.015625f - mu*mu + 1e-5f);
#pragma unroll
    for (int j = 0; j < 8; ++j) {
      int c = q*16 + j*2;
      float a0 = (xv[j*2+0] - mu) * rstd * n2g[c]   + n2b[c];
      float a1 = (xv[j*2+1] - mu) * rstd * n2g[c+1] + n2b[c+1];
      unsigned pk = (unsigned)f2bf(a0) | ((unsigned)f2bf(a1) << 16);
      *(unsigned*)&xn[t][c] = pk;
    }
  }

  // ---- depthwise conv accumulate in regs (reads x1h only) ----
  float cacc[16];
  {
    const int cty = lane >> 3, ctx = lane & 7;
#pragma unroll
    for (int i = 0; i < 16; ++i) {
      const int c = g*16 + i;
      const float* wc = dww + c*9;
      float acc = dwb[c];
#pragma unroll
      for (int dy = 0; dy < 3; ++dy)
#pragma unroll
        for (int dx = 0; dx < 3; ++dx)
          acc += wc[dy*3 + dx] * bf2f(x1h[(cty + dy)*10 + (ctx + dx)][c]);
      cacc[i] = acc;
    }
  }
  __syncthreads();   // xn ready; all LN reads of ob done

  // conv + bias into ob (wave g owns cols g*16..g*16+15; same wave merges FFN later)
#pragma unroll
  for (int i = 0; i < 16; ++i)
    ob[lane][g*16 + i] += cacc[i];

  // ---- GEMM1: hidden = GELU(xn @ w1 + b1); wave g owns hidden cols g*64..g*64+63 ----
  {
    bf16x8 afr[4][2];
#pragma unroll
    for (int mt = 0; mt < 4; ++mt)
#pragma unroll
      for (int ks = 0; ks < 2; ++ks)
        afr[mt][ks] = *(const bf16x8*)&xn[mt*16 + lr][ks*32 + lg*8];

#pragma unroll
    for (int nt = 0; nt < 4; ++nt) {
      const int n = g*64 + nt*16 + lr;
      bf16x8 bfr[2];
#pragma unroll
      for (int ks = 0; ks < 2; ++ks)
#pragma unroll
        for (int j = 0; j < 8; ++j) {
          const int k = ks*32 + lg*8 + j;
          bfr[ks][j] = (short)f2bf(w1[k*256 + n]);
        }
      f32x4 d[4] = {{0,0,0,0},{0,0,0,0},{0,0,0,0},{0,0,0,0}};
#pragma unroll
      for (int mt = 0; mt < 4; ++mt)
#pragma unroll
        for (int ks = 0; ks < 2; ++ks)
          d[mt] = __builtin_amdgcn_mfma_f32_16x16x32_bf16(afr[mt][ks], bfr[ks], d[mt], 0, 0, 0);
      const float b1n = b1[n];
#pragma unroll
      for (int mt = 0; mt < 4; ++mt)
#pragma unroll
        for (int r = 0; r < 4; ++r) {
          float h = d[mt][r] + b1n;
          h = 0.5f * h * (1.f + erff(h * 0.70710678118654752f));  // exact GELU
          hid[mt*16 + lg*4 + r][n] = f2bf(h);
        }
    }
  }
  __syncthreads();   // hid ready

  // ---- GEMM2: ffn_out = hidden @ w2 + b2; wave g owns out cols g*16..g*16+15 ----
  {
    f32x4 d2[4] = {{0,0,0,0},{0,0,0,0},{0,0,0,0},{0,0,0,0}};
#pragma unroll
    for (int ks = 0; ks < 8; ++ks) {
      bf16x8 bfr;
#pragma unroll
      for (int j = 0; j < 8; ++j) {
        const int k = ks*32 + lg*8 + j;
        bfr[j] = (short)f2bf(w2[k*64 + g*16 + lr]);
      }
#pragma unroll
      for (int mt = 0; mt < 4; ++mt) {
        const bf16x8 af = *(const bf16x8*)&hid[mt*16 + lr][ks*32 + lg*8];
        d2[mt] = __builtin_amdgcn_mfma_f32_16x16x32_bf16(af, bfr, d2[mt], 0, 0, 0);
      }
    }
    const float b2n = b2[g*16 + lr];
#pragma unroll
    for (int mt = 0; mt < 4; ++mt)
#pragma unroll
      for (int r = 0; r < 4; ++r)
        ob[mt*16 + lg*4 + r][g*16 + lr] += d2[mt][r] + b2n;
  }
  __syncthreads();

  // ---- write out (B,C,H,W) ----
#pragma unroll
  for (int i = 0; i < 16; ++i) {
    int idx = i * 256 + tid;
    int c = idx >> 6, t = idx & 63;
    int ty = t >> 3, tx = t & 7;
    out[(((size_t)b*64 + c)*256 + (y0 + ty))*256 + (x0 + tx)] = ob[t][c];
  }
}

extern "C" void kernel_launch(void* const* d_in, const int* in_sizes, int n_in,
                              void* d_out, int out_size, void* d_ws, size_t ws_size,
                              hipStream_t stream) {
  const float* x      = (const float*)d_in[0];
  const float* qkv_w  = (const float*)d_in[1];
  const float* qkv_b  = (const float*)d_in[2];
  const float* proj_w = (const float*)d_in[3];
  const float* proj_b = (const float*)d_in[4];
  const float* rpb    = (const float*)d_in[5];
  const float* n1g    = (const float*)d_in[6];
  const float* n1b    = (const float*)d_in[7];
  const float* n2g    = (const float*)d_in[8];
  const float* n2b    = (const float*)d_in[9];
  const float* w1     = (const float*)d_in[10];
  const float* b1     = (const float*)d_in[11];
  const float* w2     = (const float*)d_in[12];
  const float* b2     = (const float*)d_in[13];
  const float* dww    = (const float*)d_in[14];
  const float* dwb    = (const float*)d_in[15];
  float* out = (float*)d_out;
  float* x1  = (float*)d_ws;   // 8*256*256*64 floats = 128 MiB

  win_attn_kernel<<<8192, 256, 0, stream>>>(x, qkv_w, qkv_b, proj_w, proj_b,
                                            rpb, n1g, n1b, x1);
  ffn_conv_kernel<<<8192, 256, 0, stream>>>(x1, n2g, n2b, w1, b1, w2, b2,
                                            dww, dwb, out);
}

// Round 3
// 548.077 us; speedup vs baseline: 5.8073x; 2.7126x over previous
//
#include <hip/hip_runtime.h>
#include <cmath>

// LeWin block: B=8, C=64, H=W=256, ws=8, heads=4, hd=16, hidden=256.
// Kernel A: LN1 + window attention (bf16 MFMA) + proj + residual -> x1 (B,H,W,C)
// Kernel B: LN2 + FFN (bf16 MFMA) + depthwise conv + adds -> out (B,C,H,W)

typedef __attribute__((ext_vector_type(8))) short bf16x8;
typedef __attribute__((ext_vector_type(4))) float f32x4;

static __device__ __forceinline__ unsigned short f2bf(float f) {
  union { float f; unsigned u; } v; v.f = f;
  unsigned r = v.u + 0x7FFF + ((v.u >> 16) & 1);   // round-to-nearest-even
  return (unsigned short)(r >> 16);
}
static __device__ __forceinline__ float bf2f(unsigned short u) {
  union { unsigned u; float f; } v; v.u = ((unsigned)u) << 16;
  return v.f;
}

// ==================== Kernel A: MFMA window attention ====================
#define QKP 24    // qh/kh pitch (shorts)
#define SPP 72    // sp (P matrix) pitch
#define VTP 72    // vt (V^T) pitch

__global__ __launch_bounds__(256, 2)
void win_attn_kernel(const float* __restrict__ x,
                     const float* __restrict__ qkv_w,
                     const float* __restrict__ qkv_b,
                     const float* __restrict__ proj_w,
                     const float* __restrict__ proj_b,
                     const float* __restrict__ rpb,
                     const float* __restrict__ n1g,
                     const float* __restrict__ n1b,
                     float* __restrict__ x1)
{
  __shared__ float          xw[64][68];     // raw window fp32 (residual)     17408B
  __shared__ unsigned short xn[64][72];     // LN1 bf16; later reused as oh    9216B
  __shared__ unsigned short hbuf[4][5760];  // per-head: vt | (qh,kh)∪sp      46080B
  __shared__ float          rpb_l[900];     // rel-pos table                   3600B
  __shared__ unsigned char  ridx_l[4096];   // (i,j) -> rpb row                4096B

  const int tid = threadIdx.x;
  const int wid = blockIdx.x;
  const int b  = wid >> 10;
  const int wy = (wid >> 5) & 31;
  const int wx = wid & 31;
  const int y0 = wy << 3, x0 = wx << 3;

  // ---- load + transpose (B,C,H,W) -> xw[token][channel] ----
  const size_t imgbase = (size_t)b * 64 * 65536;
#pragma unroll
  for (int i = 0; i < 16; ++i) {
    int idx = i * 256 + tid;
    int c = idx >> 6, t = idx & 63;
    xw[t][c] = x[imgbase + ((size_t)c << 16) + (size_t)(y0 + (t >> 3)) * 256 + (x0 + (t & 7))];
  }
  for (int u = tid; u < 900; u += 256) rpb_l[u] = rpb[u];
  for (int u = tid; u < 4096; u += 256) {
    int i = u >> 6, j = u & 63;
    ridx_l[u] = (unsigned char)(((i >> 3) - (j >> 3) + 7) * 15 + ((i & 7) - (j & 7) + 7));
  }
  __syncthreads();

  // ---- LayerNorm1 (4 lanes per token) -> xn bf16 ----
  {
    const int t = tid >> 2, q = tid & 3;
    float xv[16], s = 0.f, s2 = 0.f;
#pragma unroll
    for (int i = 0; i < 16; ++i) { float v = xw[t][q*16 + i]; xv[i] = v; s += v; s2 += v*v; }
    s  += __shfl_xor(s, 1);  s  += __shfl_xor(s, 2);
    s2 += __shfl_xor(s2, 1); s2 += __shfl_xor(s2, 2);
    const float mu   = s * 0.015625f;
    const float rstd = rsqrtf(s2 * 0.015625f - mu*mu + 1e-5f);
#pragma unroll
    for (int jj = 0; jj < 8; ++jj) {
      int c = q*16 + jj*2;
      float a0 = (xv[jj*2+0] - mu) * rstd * n1g[c]   + n1b[c];
      float a1 = (xv[jj*2+1] - mu) * rstd * n1g[c+1] + n1b[c+1];
      *(unsigned*)&xn[t][c] = (unsigned)f2bf(a0) | ((unsigned)f2bf(a1) << 16);
    }
  }
  __syncthreads();

  const int lane = tid & 63;
  const int g    = tid >> 6;       // wave = head
  const int lr   = lane & 15;
  const int lg   = lane >> 4;

  unsigned short* vt = &hbuf[g][0];      // [16][VTP]   V^T
  unsigned short* qh = &hbuf[g][1152];   // [64][QKP]   Q (dead after S)
  unsigned short* kh = &hbuf[g][2688];   // [64][QKP]   K (dead after S)
  unsigned short* sp = &hbuf[g][1152];   // [64][SPP]   P (aliases qh/kh)

  // A-fragments of LN1 output (shared by all of QKV)
  bf16x8 afr[4][2];
#pragma unroll
  for (int mt = 0; mt < 4; ++mt)
#pragma unroll
    for (int ks = 0; ks < 2; ++ks)
      afr[mt][ks] = *(const bf16x8*)&xn[mt*16 + lr][ks*32 + lg*8];
  __syncthreads();   // xn dead everywhere -> reusable as oh

  // ---- QKV for head g (24 MFMA) ----
  {
    f32x4 dq[4], dk[4], dv[4];
#pragma unroll
    for (int mt = 0; mt < 4; ++mt) {
      dq[mt] = (f32x4){0,0,0,0}; dk[mt] = (f32x4){0,0,0,0}; dv[mt] = (f32x4){0,0,0,0};
    }
    const int nbq = g*16, nbk = 64 + g*16, nbv = 128 + g*16;
#pragma unroll
    for (int ks = 0; ks < 2; ++ks) {
      bf16x8 bq, bk, bv;
#pragma unroll
      for (int j = 0; j < 8; ++j) {
        const int k = ks*32 + lg*8 + j;
        bq[j] = (short)f2bf(qkv_w[k*192 + nbq + lr]);
        bk[j] = (short)f2bf(qkv_w[k*192 + nbk + lr]);
        bv[j] = (short)f2bf(qkv_w[k*192 + nbv + lr]);
      }
#pragma unroll
      for (int mt = 0; mt < 4; ++mt) {
        dq[mt] = __builtin_amdgcn_mfma_f32_16x16x32_bf16(afr[mt][ks], bq, dq[mt], 0, 0, 0);
        dk[mt] = __builtin_amdgcn_mfma_f32_16x16x32_bf16(afr[mt][ks], bk, dk[mt], 0, 0, 0);
        dv[mt] = __builtin_amdgcn_mfma_f32_16x16x32_bf16(afr[mt][ks], bv, dv[mt], 0, 0, 0);
      }
    }
    const float bq_ = qkv_b[nbq + lr], bk_ = qkv_b[nbk + lr], bv_ = qkv_b[nbv + lr];
#pragma unroll
    for (int mt = 0; mt < 4; ++mt)
#pragma unroll
      for (int r = 0; r < 4; ++r) {
        const int tok = mt*16 + lg*4 + r;
        qh[tok*QKP + lr] = f2bf((dq[mt][r] + bq_) * 0.25f);   // fold scale into q
        kh[tok*QKP + lr] = f2bf(dk[mt][r] + bk_);
        vt[lr*VTP + tok] = f2bf(dv[mt][r] + bv_);
      }
  }

  // ---- S^T = K @ Q^T (16 MFMA, K-dim 16 zero-padded to 32), bias, softmax ----
  {
    const bf16x8 zf = (bf16x8){0,0,0,0,0,0,0,0};
    bf16x8 kfr[4], qfr[4];
#pragma unroll
    for (int mt = 0; mt < 4; ++mt)
      kfr[mt] = (lg < 2) ? *(const bf16x8*)&kh[(mt*16 + lr)*QKP + lg*8] : zf;
#pragma unroll
    for (int nt = 0; nt < 4; ++nt)
      qfr[nt] = (lg < 2) ? *(const bf16x8*)&qh[(nt*16 + lr)*QKP + lg*8] : zf;

    f32x4 s[4][4];
#pragma unroll
    for (int mt = 0; mt < 4; ++mt)
#pragma unroll
      for (int nt = 0; nt < 4; ++nt) {
        s[mt][nt] = (f32x4){0,0,0,0};
        s[mt][nt] = __builtin_amdgcn_mfma_f32_16x16x32_bf16(kfr[mt], qfr[nt], s[mt][nt], 0, 0, 0);
      }

    // rel-pos bias: lane holds S^T[j = mt*16+lg*4+r][i = nt*16+lr]
#pragma unroll
    for (int nt = 0; nt < 4; ++nt) {
      const int i = nt*16 + lr;
#pragma unroll
      for (int mt = 0; mt < 4; ++mt)
#pragma unroll
        for (int r = 0; r < 4; ++r) {
          const int j = mt*16 + lg*4 + r;
          s[mt][nt][r] += rpb_l[(int)ridx_l[i*64 + j] * 4 + g];
        }
    }

    // softmax over j for each i; i lives in (nt, lr); j spread over (mt,r) in-lane + lg cross-lane
#pragma unroll
    for (int nt = 0; nt < 4; ++nt) {
      float mx = -1e30f;
#pragma unroll
      for (int mt = 0; mt < 4; ++mt)
#pragma unroll
        for (int r = 0; r < 4; ++r) mx = fmaxf(mx, s[mt][nt][r]);
      mx = fmaxf(mx, __shfl_xor(mx, 16));
      mx = fmaxf(mx, __shfl_xor(mx, 32));
      float sum = 0.f;
#pragma unroll
      for (int mt = 0; mt < 4; ++mt)
#pragma unroll
        for (int r = 0; r < 4; ++r) { float e = __expf(s[mt][nt][r] - mx); s[mt][nt][r] = e; sum += e; }
      sum += __shfl_xor(sum, 16);
      sum += __shfl_xor(sum, 32);
      const float rs = 1.f / sum;
      const int i = nt*16 + lr;
#pragma unroll
      for (int mt = 0; mt < 4; ++mt)
#pragma unroll
        for (int r = 0; r < 4; ++r)
          sp[i*SPP + mt*16 + lg*4 + r] = f2bf(s[mt][nt][r] * rs);   // P row-major
    }
  }

  // ---- O = P @ V (8 MFMA) -> oh (reuses xn) ----
  unsigned short* ohp = &xn[0][0];
  {
    f32x4 o[4];
#pragma unroll
    for (int mt = 0; mt < 4; ++mt) o[mt] = (f32x4){0,0,0,0};
#pragma unroll
    for (int ks = 0; ks < 2; ++ks) {
      const bf16x8 bv_ = *(const bf16x8*)&vt[lr*VTP + ks*32 + lg*8];
#pragma unroll
      for (int mt = 0; mt < 4; ++mt) {
        const bf16x8 af = *(const bf16x8*)&sp[(mt*16 + lr)*SPP + ks*32 + lg*8];
        o[mt] = __builtin_amdgcn_mfma_f32_16x16x32_bf16(af, bv_, o[mt], 0, 0, 0);
      }
    }
#pragma unroll
    for (int mt = 0; mt < 4; ++mt)
#pragma unroll
      for (int r = 0; r < 4; ++r)
        ohp[(mt*16 + lg*4 + r)*72 + g*16 + lr] = f2bf(o[mt][r]);
  }
  __syncthreads();   // oh ready for all waves

  // ---- proj (8 MFMA) + bias + residual -> x1 ----
  {
    bf16x8 pa[4][2];
#pragma unroll
    for (int mt = 0; mt < 4; ++mt)
#pragma unroll
      for (int ks = 0; ks < 2; ++ks)
        pa[mt][ks] = *(const bf16x8*)&ohp[(mt*16 + lr)*72 + ks*32 + lg*8];
    f32x4 d2[4];
#pragma unroll
    for (int mt = 0; mt < 4; ++mt) d2[mt] = (f32x4){0,0,0,0};
#pragma unroll
    for (int ks = 0; ks < 2; ++ks) {
      bf16x8 pb;
#pragma unroll
      for (int j = 0; j < 8; ++j)
        pb[j] = (short)f2bf(proj_w[(ks*32 + lg*8 + j)*64 + g*16 + lr]);
#pragma unroll
      for (int mt = 0; mt < 4; ++mt)
        d2[mt] = __builtin_amdgcn_mfma_f32_16x16x32_bf16(pa[mt][ks], pb, d2[mt], 0, 0, 0);
    }
    const float pbias = proj_b[g*16 + lr];
#pragma unroll
    for (int mt = 0; mt < 4; ++mt)
#pragma unroll
      for (int r = 0; r < 4; ++r) {
        const int tok = mt*16 + lg*4 + r;
        const float val = d2[mt][r] + pbias + xw[tok][g*16 + lr];
        x1[(((size_t)b*256 + y0 + (tok >> 3))*256 + x0 + (tok & 7))*64 + g*16 + lr] = val;
      }
  }
}

// ==================== Kernel B: LN2 + MFMA FFN + dwconv (unchanged) ====================
#define HLP 66    // halo pitch (bf16), pixel-major [100][HLP]
#define OBP 68    // ob pitch (f32)
#define XNP 72    // xn pitch (bf16)
#define HP  264   // hid pitch (bf16)

__global__ __launch_bounds__(256, 2)
void ffn_conv_kernel(const float* __restrict__ x1,
                     const float* __restrict__ n2g, const float* __restrict__ n2b,
                     const float* __restrict__ w1,  const float* __restrict__ b1,
                     const float* __restrict__ w2,  const float* __restrict__ b2,
                     const float* __restrict__ dww, const float* __restrict__ dwb,
                     float* __restrict__ out)
{
  __shared__ unsigned short x1h[100][HLP];  // bf16 halo, pixel-major
  __shared__ float          ob[64][OBP];    // residual + conv + ffn accumulator
  __shared__ unsigned short xn[64][XNP];    // LN2 output bf16
  __shared__ unsigned short hid[64][HP];    // hidden bf16 (64 tok x 256)

  const int tid = threadIdx.x;
  const int wid = blockIdx.x;
  const int b  = wid >> 10;
  const int wy = (wid >> 5) & 31;
  const int wx = wid & 31;
  const int y0 = wy << 3, x0 = wx << 3;

  // ---- halo load (100 px x 64 ch), fp32 -> bf16, pixel-major ----
#pragma unroll
  for (int i = 0; i < 13; ++i) {
    int u = i * 256 + tid;                 // 3200 float2 units
    if (u < 3200) {
      int p = u >> 5, c2 = (u & 31) << 1;
      int py = p / 10, px = p - py*10;
      int gy = y0 + py - 1, gx = x0 + px - 1;
      float vx = 0.f, vy = 0.f;
      if ((unsigned)gy < 256u && (unsigned)gx < 256u) {
        const float2 v = *(const float2*)&x1[(((size_t)b*256 + gy)*256 + gx)*64 + c2];
        vx = v.x; vy = v.y;
      }
      unsigned pk = (unsigned)f2bf(vx) | ((unsigned)f2bf(vy) << 16);
      *(unsigned*)&x1h[p][c2] = pk;
    }
  }

  // ---- residual init: ob[t][c] = x1 window (fp32, coalesced float4) ----
#pragma unroll
  for (int i = 0; i < 4; ++i) {
    int u = i * 256 + tid;                 // 1024 float4 units
    int t = u >> 4, c4 = (u & 15) << 2;
    int ty = t >> 3, tx = t & 7;
    const float4 v = *(const float4*)&x1[(((size_t)b*256 + y0 + ty)*256 + x0 + tx)*64 + c4];
    *(float4*)&ob[t][c4] = v;
  }
  __syncthreads();

  const int lane = tid & 63;
  const int g    = tid >> 6;     // wave 0..3
  const int lr   = lane & 15;
  const int lg   = lane >> 4;

  // ---- LayerNorm2 (4 lanes per token), write xn bf16 ----
  {
    const int t = tid >> 2, q = tid & 3;
    float xv[16], s = 0.f, s2 = 0.f;
#pragma unroll
    for (int i = 0; i < 4; ++i) {
      const float4 v = *(const float4*)&ob[t][q*16 + i*4];
      xv[i*4+0] = v.x; xv[i*4+1] = v.y; xv[i*4+2] = v.z; xv[i*4+3] = v.w;
      s += v.x + v.y + v.z + v.w;
      s2 += v.x*v.x + v.y*v.y + v.z*v.z + v.w*v.w;
    }
    s  += __shfl_xor(s, 1);  s  += __shfl_xor(s, 2);
    s2 += __shfl_xor(s2, 1); s2 += __shfl_xor(s2, 2);
    const float mu   = s * 0.015625f;
    const float rstd = rsqrtf(s2 * 0.015625f - mu*mu + 1e-5f);
#pragma unroll
    for (int j = 0; j < 8; ++j) {
      int c = q*16 + j*2;
      float a0 = (xv[j*2+0] - mu) * rstd * n2g[c]   + n2b[c];
      float a1 = (xv[j*2+1] - mu) * rstd * n2g[c+1] + n2b[c+1];
      unsigned pk = (unsigned)f2bf(a0) | ((unsigned)f2bf(a1) << 16);
      *(unsigned*)&xn[t][c] = pk;
    }
  }

  // ---- depthwise conv accumulate in regs (reads x1h only) ----
  float cacc[16];
  {
    const int cty = lane >> 3, ctx = lane & 7;
#pragma unroll
    for (int i = 0; i < 16; ++i) {
      const int c = g*16 + i;
      const float* wc = dww + c*9;
      float acc = dwb[c];
#pragma unroll
      for (int dy = 0; dy < 3; ++dy)
#pragma unroll
        for (int dx = 0; dx < 3; ++dx)
          acc += wc[dy*3 + dx] * bf2f(x1h[(cty + dy)*10 + (ctx + dx)][c]);
      cacc[i] = acc;
    }
  }
  __syncthreads();   // xn ready; all LN reads of ob done

  // conv + bias into ob (wave g owns cols g*16..g*16+15; same wave merges FFN later)
#pragma unroll
  for (int i = 0; i < 16; ++i)
    ob[lane][g*16 + i] += cacc[i];

  // ---- GEMM1: hidden = GELU(xn @ w1 + b1); wave g owns hidden cols g*64..g*64+63 ----
  {
    bf16x8 afr[4][2];
#pragma unroll
    for (int mt = 0; mt < 4; ++mt)
#pragma unroll
      for (int ks = 0; ks < 2; ++ks)
        afr[mt][ks] = *(const bf16x8*)&xn[mt*16 + lr][ks*32 + lg*8];

#pragma unroll
    for (int nt = 0; nt < 4; ++nt) {
      const int n = g*64 + nt*16 + lr;
      bf16x8 bfr[2];
#pragma unroll
      for (int ks = 0; ks < 2; ++ks)
#pragma unroll
        for (int j = 0; j < 8; ++j) {
          const int k = ks*32 + lg*8 + j;
          bfr[ks][j] = (short)f2bf(w1[k*256 + n]);
        }
      f32x4 d[4] = {{0,0,0,0},{0,0,0,0},{0,0,0,0},{0,0,0,0}};
#pragma unroll
      for (int mt = 0; mt < 4; ++mt)
#pragma unroll
        for (int ks = 0; ks < 2; ++ks)
          d[mt] = __builtin_amdgcn_mfma_f32_16x16x32_bf16(afr[mt][ks], bfr[ks], d[mt], 0, 0, 0);
      const float b1n = b1[n];
#pragma unroll
      for (int mt = 0; mt < 4; ++mt)
#pragma unroll
        for (int r = 0; r < 4; ++r) {
          float h = d[mt][r] + b1n;
          h = 0.5f * h * (1.f + erff(h * 0.70710678118654752f));  // exact GELU
          hid[mt*16 + lg*4 + r][n] = f2bf(h);
        }
    }
  }
  __syncthreads();   // hid ready

  // ---- GEMM2: ffn_out = hidden @ w2 + b2; wave g owns out cols g*16..g*16+15 ----
  {
    f32x4 d2[4] = {{0,0,0,0},{0,0,0,0},{0,0,0,0},{0,0,0,0}};
#pragma unroll
    for (int ks = 0; ks < 8; ++ks) {
      bf16x8 bfr;
#pragma unroll
      for (int j = 0; j < 8; ++j) {
        const int k = ks*32 + lg*8 + j;
        bfr[j] = (short)f2bf(w2[k*64 + g*16 + lr]);
      }
#pragma unroll
      for (int mt = 0; mt < 4; ++mt) {
        const bf16x8 af = *(const bf16x8*)&hid[mt*16 + lr][ks*32 + lg*8];
        d2[mt] = __builtin_amdgcn_mfma_f32_16x16x32_bf16(af, bfr, d2[mt], 0, 0, 0);
      }
    }
    const float b2n = b2[g*16 + lr];
#pragma unroll
    for (int mt = 0; mt < 4; ++mt)
#pragma unroll
      for (int r = 0; r < 4; ++r)
        ob[mt*16 + lg*4 + r][g*16 + lr] += d2[mt][r] + b2n;
  }
  __syncthreads();

  // ---- write out (B,C,H,W) ----
#pragma unroll
  for (int i = 0; i < 16; ++i) {
    int idx = i * 256 + tid;
    int c = idx >> 6, t = idx & 63;
    int ty = t >> 3, tx = t & 7;
    out[(((size_t)b*64 + c)*256 + (y0 + ty))*256 + (x0 + tx)] = ob[t][c];
  }
}

extern "C" void kernel_launch(void* const* d_in, const int* in_sizes, int n_in,
                              void* d_out, int out_size, void* d_ws, size_t ws_size,
                              hipStream_t stream) {
  const float* x      = (const float*)d_in[0];
  const float* qkv_w  = (const float*)d_in[1];
  const float* qkv_b  = (const float*)d_in[2];
  const float* proj_w = (const float*)d_in[3];
  const float* proj_b = (const float*)d_in[4];
  const float* rpb    = (const float*)d_in[5];
  const float* n1g    = (const float*)d_in[6];
  const float* n1b    = (const float*)d_in[7];
  const float* n2g    = (const float*)d_in[8];
  const float* n2b    = (const float*)d_in[9];
  const float* w1     = (const float*)d_in[10];
  const float* b1     = (const float*)d_in[11];
  const float* w2     = (const float*)d_in[12];
  const float* b2     = (const float*)d_in[13];
  const float* dww    = (const float*)d_in[14];
  const float* dwb    = (const float*)d_in[15];
  float* out = (float*)d_out;
  float* x1  = (float*)d_ws;   // 8*256*256*64 floats = 128 MiB

  win_attn_kernel<<<8192, 256, 0, stream>>>(x, qkv_w, qkv_b, proj_w, proj_b,
                                            rpb, n1g, n1b, x1);
  ffn_conv_kernel<<<8192, 256, 0, stream>>>(x1, n2g, n2b, w1, b1, w2, b2,
                                            dww, dwb, out);
}

// Round 4
// 408.723 us; speedup vs baseline: 7.7873x; 1.3409x over previous
//
#include <hip/hip_runtime.h>
#include <cmath>

// LeWin block: B=8, C=64, H=W=256, ws=8, heads=4, hd=16, hidden=256.
// Kernel P: pack weights -> bf16 transposed [n][k] in workspace
// Kernel A: LN1 + window attention (bf16 MFMA) + proj + residual -> x1 bf16 (B,H,W,C)
// Kernel B: LN2 + FFN (bf16 MFMA, 2 hidden halves) + depthwise conv + adds -> out (B,C,H,W)

typedef __attribute__((ext_vector_type(8))) short bf16x8;
typedef __attribute__((ext_vector_type(4))) float f32x4;

static __device__ __forceinline__ unsigned short f2bf(float f) {
  union { float f; unsigned u; } v; v.f = f;
  unsigned r = v.u + 0x7FFF + ((v.u >> 16) & 1);   // round-to-nearest-even
  return (unsigned short)(r >> 16);
}
static __device__ __forceinline__ float bf2f(unsigned short u) {
  union { unsigned u; float f; } v; v.u = ((unsigned)u) << 16;
  return v.f;
}
static __device__ __forceinline__ float bf2f_s(short s) { return bf2f((unsigned short)s); }

// ==================== Kernel P: weight packing ====================
// qkvt [192][64], projt [64][64], w1t [256][64], w2t [64][256]  (bf16, k-contiguous)
__global__ void pack_weights_kernel(const float* __restrict__ qkv_w,
                                    const float* __restrict__ proj_w,
                                    const float* __restrict__ w1,
                                    const float* __restrict__ w2,
                                    unsigned short* __restrict__ qkvt,
                                    unsigned short* __restrict__ projt,
                                    unsigned short* __restrict__ w1t,
                                    unsigned short* __restrict__ w2t) {
  const int t = blockIdx.x * 256 + threadIdx.x;   // 0..16383
  {
    const int n = t >> 6, k = t & 63;
    if (n < 192) qkvt[t] = f2bf(qkv_w[k * 192 + n]);
    if (n < 64)  projt[t] = f2bf(proj_w[k * 64 + n]);
    w1t[t] = f2bf(w1[k * 256 + n]);                 // n in 0..255
  }
  {
    const int n = t >> 8, k = t & 255;
    w2t[t] = f2bf(w2[k * 64 + n]);
  }
}

// ==================== Kernel A: MFMA window attention ====================
#define QKP 24    // qh/kh pitch (shorts)
#define SPP 72    // sp (P matrix) pitch
#define VTP 72    // vt (V^T) pitch

__global__ __launch_bounds__(256, 2)
void win_attn_kernel(const float* __restrict__ x,
                     const unsigned short* __restrict__ qkvt,
                     const float* __restrict__ qkv_b,
                     const unsigned short* __restrict__ projt,
                     const float* __restrict__ proj_b,
                     const float* __restrict__ rpb,
                     const float* __restrict__ n1g,
                     const float* __restrict__ n1b,
                     unsigned short* __restrict__ x1b)
{
  __shared__ float          xw[64][68];     // raw window fp32 (residual)
  __shared__ unsigned short xn[64][72];     // LN1 bf16; reused as oh; reused as x1 staging
  __shared__ unsigned short hbuf[4][5760];  // per-head: vt | (qh,kh)∪sp
  __shared__ float          rpb_l[900];
  __shared__ unsigned char  ridx_l[4096];

  const int tid = threadIdx.x;
  const int wid = blockIdx.x;
  const int b  = wid >> 10;
  const int wy = (wid >> 5) & 31;
  const int wx = wid & 31;
  const int y0 = wy << 3, x0 = wx << 3;

  // ---- load + transpose (B,C,H,W) -> xw[token][channel] ----
  const size_t imgbase = (size_t)b * 64 * 65536;
#pragma unroll
  for (int i = 0; i < 16; ++i) {
    int idx = i * 256 + tid;
    int c = idx >> 6, t = idx & 63;
    xw[t][c] = x[imgbase + ((size_t)c << 16) + (size_t)(y0 + (t >> 3)) * 256 + (x0 + (t & 7))];
  }
  for (int u = tid; u < 900; u += 256) rpb_l[u] = rpb[u];
  for (int u = tid; u < 4096; u += 256) {
    int i = u >> 6, j = u & 63;
    ridx_l[u] = (unsigned char)(((i >> 3) - (j >> 3) + 7) * 15 + ((i & 7) - (j & 7) + 7));
  }
  __syncthreads();

  // ---- LayerNorm1 (4 lanes per token) -> xn bf16 ----
  {
    const int t = tid >> 2, q = tid & 3;
    float xv[16], s = 0.f, s2 = 0.f;
#pragma unroll
    for (int i = 0; i < 16; ++i) { float v = xw[t][q*16 + i]; xv[i] = v; s += v; s2 += v*v; }
    s  += __shfl_xor(s, 1);  s  += __shfl_xor(s, 2);
    s2 += __shfl_xor(s2, 1); s2 += __shfl_xor(s2, 2);
    const float mu   = s * 0.015625f;
    const float rstd = rsqrtf(s2 * 0.015625f - mu*mu + 1e-5f);
#pragma unroll
    for (int jj = 0; jj < 8; ++jj) {
      int c = q*16 + jj*2;
      float a0 = (xv[jj*2+0] - mu) * rstd * n1g[c]   + n1b[c];
      float a1 = (xv[jj*2+1] - mu) * rstd * n1g[c+1] + n1b[c+1];
      *(unsigned*)&xn[t][c] = (unsigned)f2bf(a0) | ((unsigned)f2bf(a1) << 16);
    }
  }
  __syncthreads();

  const int lane = tid & 63;
  const int g    = tid >> 6;       // wave = head
  const int lr   = lane & 15;
  const int lg   = lane >> 4;

  unsigned short* vt = &hbuf[g][0];      // [16][VTP]   V^T
  unsigned short* qh = &hbuf[g][1152];   // [64][QKP]   Q (dead after S)
  unsigned short* kh = &hbuf[g][2688];   // [64][QKP]   K (dead after S)
  unsigned short* sp = &hbuf[g][1152];   // [64][SPP]   P (aliases qh/kh)

  // A-fragments of LN1 output (shared by all of QKV)
  bf16x8 afr[4][2];
#pragma unroll
  for (int mt = 0; mt < 4; ++mt)
#pragma unroll
    for (int ks = 0; ks < 2; ++ks)
      afr[mt][ks] = *(const bf16x8*)&xn[mt*16 + lr][ks*32 + lg*8];
  __syncthreads();   // xn dead everywhere -> reusable as oh

  // ---- QKV for head g (24 MFMA), B-frags as vector loads from packed qkvt ----
  {
    f32x4 dq[4], dk[4], dv[4];
#pragma unroll
    for (int mt = 0; mt < 4; ++mt) {
      dq[mt] = (f32x4){0,0,0,0}; dk[mt] = (f32x4){0,0,0,0}; dv[mt] = (f32x4){0,0,0,0};
    }
    const int nbq = g*16, nbk = 64 + g*16, nbv = 128 + g*16;
#pragma unroll
    for (int ks = 0; ks < 2; ++ks) {
      const bf16x8 bq = *(const bf16x8*)&qkvt[(nbq + lr)*64 + ks*32 + lg*8];
      const bf16x8 bk = *(const bf16x8*)&qkvt[(nbk + lr)*64 + ks*32 + lg*8];
      const bf16x8 bv = *(const bf16x8*)&qkvt[(nbv + lr)*64 + ks*32 + lg*8];
#pragma unroll
      for (int mt = 0; mt < 4; ++mt) {
        dq[mt] = __builtin_amdgcn_mfma_f32_16x16x32_bf16(afr[mt][ks], bq, dq[mt], 0, 0, 0);
        dk[mt] = __builtin_amdgcn_mfma_f32_16x16x32_bf16(afr[mt][ks], bk, dk[mt], 0, 0, 0);
        dv[mt] = __builtin_amdgcn_mfma_f32_16x16x32_bf16(afr[mt][ks], bv, dv[mt], 0, 0, 0);
      }
    }
    const float bq_ = qkv_b[nbq + lr], bk_ = qkv_b[nbk + lr], bv_ = qkv_b[nbv + lr];
#pragma unroll
    for (int mt = 0; mt < 4; ++mt)
#pragma unroll
      for (int r = 0; r < 4; ++r) {
        const int tok = mt*16 + lg*4 + r;
        qh[tok*QKP + lr] = f2bf((dq[mt][r] + bq_) * 0.25f);   // fold scale into q
        kh[tok*QKP + lr] = f2bf(dk[mt][r] + bk_);
        vt[lr*VTP + tok] = f2bf(dv[mt][r] + bv_);
      }
  }

  // ---- S^T = K @ Q^T (16 MFMA, K-dim 16 zero-padded to 32), bias, softmax ----
  {
    const bf16x8 zf = (bf16x8){0,0,0,0,0,0,0,0};
    bf16x8 kfr[4], qfr[4];
#pragma unroll
    for (int mt = 0; mt < 4; ++mt)
      kfr[mt] = (lg < 2) ? *(const bf16x8*)&kh[(mt*16 + lr)*QKP + lg*8] : zf;
#pragma unroll
    for (int nt = 0; nt < 4; ++nt)
      qfr[nt] = (lg < 2) ? *(const bf16x8*)&qh[(nt*16 + lr)*QKP + lg*8] : zf;

    f32x4 s[4][4];
#pragma unroll
    for (int mt = 0; mt < 4; ++mt)
#pragma unroll
      for (int nt = 0; nt < 4; ++nt) {
        s[mt][nt] = (f32x4){0,0,0,0};
        s[mt][nt] = __builtin_amdgcn_mfma_f32_16x16x32_bf16(kfr[mt], qfr[nt], s[mt][nt], 0, 0, 0);
      }

#pragma unroll
    for (int nt = 0; nt < 4; ++nt) {
      const int i = nt*16 + lr;
#pragma unroll
      for (int mt = 0; mt < 4; ++mt)
#pragma unroll
        for (int r = 0; r < 4; ++r) {
          const int j = mt*16 + lg*4 + r;
          s[mt][nt][r] += rpb_l[(int)ridx_l[i*64 + j] * 4 + g];
        }
    }

#pragma unroll
    for (int nt = 0; nt < 4; ++nt) {
      float mx = -1e30f;
#pragma unroll
      for (int mt = 0; mt < 4; ++mt)
#pragma unroll
        for (int r = 0; r < 4; ++r) mx = fmaxf(mx, s[mt][nt][r]);
      mx = fmaxf(mx, __shfl_xor(mx, 16));
      mx = fmaxf(mx, __shfl_xor(mx, 32));
      float sum = 0.f;
#pragma unroll
      for (int mt = 0; mt < 4; ++mt)
#pragma unroll
        for (int r = 0; r < 4; ++r) { float e = __expf(s[mt][nt][r] - mx); s[mt][nt][r] = e; sum += e; }
      sum += __shfl_xor(sum, 16);
      sum += __shfl_xor(sum, 32);
      const float rs = 1.f / sum;
      const int i = nt*16 + lr;
#pragma unroll
      for (int mt = 0; mt < 4; ++mt)
#pragma unroll
        for (int r = 0; r < 4; ++r)
          sp[i*SPP + mt*16 + lg*4 + r] = f2bf(s[mt][nt][r] * rs);
    }
  }

  // ---- O = P @ V (8 MFMA) -> oh (reuses xn) ----
  unsigned short* ohp = &xn[0][0];
  {
    f32x4 o[4];
#pragma unroll
    for (int mt = 0; mt < 4; ++mt) o[mt] = (f32x4){0,0,0,0};
#pragma unroll
    for (int ks = 0; ks < 2; ++ks) {
      const bf16x8 bv_ = *(const bf16x8*)&vt[lr*VTP + ks*32 + lg*8];
#pragma unroll
      for (int mt = 0; mt < 4; ++mt) {
        const bf16x8 af = *(const bf16x8*)&sp[(mt*16 + lr)*SPP + ks*32 + lg*8];
        o[mt] = __builtin_amdgcn_mfma_f32_16x16x32_bf16(af, bv_, o[mt], 0, 0, 0);
      }
    }
#pragma unroll
    for (int mt = 0; mt < 4; ++mt)
#pragma unroll
      for (int r = 0; r < 4; ++r)
        ohp[(mt*16 + lg*4 + r)*72 + g*16 + lr] = f2bf(o[mt][r]);
  }
  __syncthreads();   // oh ready for all waves

  // ---- proj (8 MFMA) + bias + residual -> stage bf16 -> x1b ----
  {
    bf16x8 pa[4][2];
#pragma unroll
    for (int mt = 0; mt < 4; ++mt)
#pragma unroll
      for (int ks = 0; ks < 2; ++ks)
        pa[mt][ks] = *(const bf16x8*)&ohp[(mt*16 + lr)*72 + ks*32 + lg*8];
    __syncthreads();   // all pa loads done; xn free for staging

    f32x4 d2[4];
#pragma unroll
    for (int mt = 0; mt < 4; ++mt) d2[mt] = (f32x4){0,0,0,0};
#pragma unroll
    for (int ks = 0; ks < 2; ++ks) {
      const bf16x8 pb = *(const bf16x8*)&projt[(g*16 + lr)*64 + ks*32 + lg*8];
#pragma unroll
      for (int mt = 0; mt < 4; ++mt)
        d2[mt] = __builtin_amdgcn_mfma_f32_16x16x32_bf16(pa[mt][ks], pb, d2[mt], 0, 0, 0);
    }
    const float pbias = proj_b[g*16 + lr];
#pragma unroll
    for (int mt = 0; mt < 4; ++mt)
#pragma unroll
      for (int r = 0; r < 4; ++r) {
        const int tok = mt*16 + lg*4 + r;
        xn[tok][g*16 + lr] = f2bf(d2[mt][r] + pbias + xw[tok][g*16 + lr]);
      }
  }
  __syncthreads();

  // ---- coalesced bf16 store of x1 window ----
#pragma unroll
  for (int i = 0; i < 2; ++i) {
    const int u = i * 256 + tid;         // 512 bf16x8 units
    const int tok = u >> 3, c8 = (u & 7) << 3;
    const bf16x8 v = *(const bf16x8*)&xn[tok][c8];
    *(bf16x8*)&x1b[(((size_t)b*256 + y0 + (tok >> 3))*256 + x0 + (tok & 7))*64 + c8] = v;
  }
}

// ==================== Kernel B: LN2 + MFMA FFN (2 halves) + dwconv ====================
__global__ __launch_bounds__(256, 3)
void ffn_conv_kernel(const unsigned short* __restrict__ x1b,
                     const float* __restrict__ n2g, const float* __restrict__ n2b,
                     const unsigned short* __restrict__ w1t, const float* __restrict__ b1,
                     const unsigned short* __restrict__ w2t, const float* __restrict__ b2,
                     const float* __restrict__ dww, const float* __restrict__ dwb,
                     float* __restrict__ out)
{
  __shared__ unsigned short xn[64][72];      //  9216 B  LN2 output bf16
  __shared__ float          ob[64][65];      // 16640 B  residual+conv+ffn accumulator (odd pitch: conflict-free)
  __shared__ unsigned short cbuf[8704];      // 17408 B  x1h [100][72] (14400B) ∪ hid [64][136]

  unsigned short (*x1h)[72]  = (unsigned short(*)[72])cbuf;   // bf16 halo, pixel-major
  unsigned short (*hid)[136] = (unsigned short(*)[136])cbuf;  // hidden half bf16

  const int tid = threadIdx.x;
  const int wid = blockIdx.x;
  const int b  = wid >> 10;
  const int wy = (wid >> 5) & 31;
  const int wx = wid & 31;
  const int y0 = wy << 3, x0 = wx << 3;

  // ---- halo load (100 px x 64 ch bf16), straight copy ----
#pragma unroll
  for (int i = 0; i < 7; ++i) {
    const int u = i * 256 + tid;               // 1600 uint2 (4-short) units
    if (u < 1600) {
      const int p = u >> 4, c4 = (u & 15) << 2;
      const int py = p / 10, px = p - py*10;
      const int gy = y0 + py - 1, gx = x0 + px - 1;
      uint2 v = make_uint2(0u, 0u);
      if ((unsigned)gy < 256u && (unsigned)gx < 256u)
        v = *(const uint2*)&x1b[(((size_t)b*256 + gy)*256 + gx)*64 + c4];
      *(uint2*)&x1h[p][c4] = v;
    }
  }
  __syncthreads();

  const int lane = tid & 63;
  const int g    = tid >> 6;     // wave 0..3
  const int lr   = lane & 15;
  const int lg   = lane >> 4;

  // ---- LayerNorm2 (4 lanes per token) from halo interior -> xn bf16 ----
  {
    const int t = tid >> 2, q = tid & 3;
    const int pp = ((t >> 3) + 1)*10 + (t & 7) + 1;
    const bf16x8 h0 = *(const bf16x8*)&x1h[pp][q*16];
    const bf16x8 h1 = *(const bf16x8*)&x1h[pp][q*16 + 8];
    float xv[16], s = 0.f, s2 = 0.f;
#pragma unroll
    for (int j = 0; j < 8; ++j) {
      xv[j]     = bf2f_s(h0[j]);
      xv[8 + j] = bf2f_s(h1[j]);
    }
#pragma unroll
    for (int j = 0; j < 16; ++j) { s += xv[j]; s2 += xv[j]*xv[j]; }
    s  += __shfl_xor(s, 1);  s  += __shfl_xor(s, 2);
    s2 += __shfl_xor(s2, 1); s2 += __shfl_xor(s2, 2);
    const float mu   = s * 0.015625f;
    const float rstd = rsqrtf(s2 * 0.015625f - mu*mu + 1e-5f);
#pragma unroll
    for (int j = 0; j < 8; ++j) {
      int c = q*16 + j*2;
      float a0 = (xv[j*2+0] - mu) * rstd * n2g[c]   + n2b[c];
      float a1 = (xv[j*2+1] - mu) * rstd * n2g[c+1] + n2b[c+1];
      *(unsigned*)&xn[t][c] = (unsigned)f2bf(a0) | ((unsigned)f2bf(a1) << 16);
    }
  }

  // ---- depthwise conv + residual -> ob (wave g owns channels g*16..+15, lane = pixel) ----
  {
    const int cty = lane >> 3, ctx = lane & 7;
    float cacc[16];
#pragma unroll
    for (int i = 0; i < 16; ++i) cacc[i] = dwb[g*16 + i];
#pragma unroll
    for (int dy = 0; dy < 3; ++dy)
#pragma unroll
      for (int dx = 0; dx < 3; ++dx) {
        const int p = (cty + dy)*10 + (ctx + dx);
        const bf16x8 h0 = *(const bf16x8*)&x1h[p][g*16];
        const bf16x8 h1 = *(const bf16x8*)&x1h[p][g*16 + 8];
#pragma unroll
        for (int i = 0; i < 8; ++i) {
          cacc[i]     += dww[(g*16 + i)*9     + dy*3 + dx] * bf2f_s(h0[i]);
          cacc[8 + i] += dww[(g*16 + 8 + i)*9 + dy*3 + dx] * bf2f_s(h1[i]);
        }
      }
    const int cp = (cty + 1)*10 + (ctx + 1);
    const bf16x8 r0 = *(const bf16x8*)&x1h[cp][g*16];
    const bf16x8 r1 = *(const bf16x8*)&x1h[cp][g*16 + 8];
#pragma unroll
    for (int i = 0; i < 8; ++i) {
      ob[lane][g*16 + i]     = bf2f_s(r0[i]) + cacc[i];
      ob[lane][g*16 + 8 + i] = bf2f_s(r1[i]) + cacc[8 + i];
    }
  }
  __syncthreads();   // xn + ob ready; x1h dead -> cbuf reusable as hid

  // ---- FFN: A-frags once; two hidden halves of 128 through aliased hid buffer ----
  bf16x8 afr[4][2];
#pragma unroll
  for (int mt = 0; mt < 4; ++mt)
#pragma unroll
    for (int ks = 0; ks < 2; ++ks)
      afr[mt][ks] = *(const bf16x8*)&xn[mt*16 + lr][ks*32 + lg*8];

  f32x4 d2[4];
#pragma unroll
  for (int mt = 0; mt < 4; ++mt) d2[mt] = (f32x4){0,0,0,0};

#pragma unroll
  for (int half = 0; half < 2; ++half) {
    // GEMM1-half: wave g owns hidden cols nl = g*32 + nt*16 + lr (nl in [0,128))
    f32x4 d1[2][4];
#pragma unroll
    for (int nt = 0; nt < 2; ++nt)
#pragma unroll
      for (int mt = 0; mt < 4; ++mt) d1[nt][mt] = (f32x4){0,0,0,0};

#pragma unroll
    for (int nt = 0; nt < 2; ++nt) {
      const int n = half*128 + g*32 + nt*16 + lr;   // global hidden index
#pragma unroll
      for (int ks = 0; ks < 2; ++ks) {
        const bf16x8 bw = *(const bf16x8*)&w1t[n*64 + ks*32 + lg*8];
#pragma unroll
        for (int mt = 0; mt < 4; ++mt)
          d1[nt][mt] = __builtin_amdgcn_mfma_f32_16x16x32_bf16(afr[mt][ks], bw, d1[nt][mt], 0, 0, 0);
      }
    }
#pragma unroll
    for (int nt = 0; nt < 2; ++nt) {
      const int n  = half*128 + g*32 + nt*16 + lr;
      const int nl = g*32 + nt*16 + lr;
      const float bb = b1[n];
#pragma unroll
      for (int mt = 0; mt < 4; ++mt)
#pragma unroll
        for (int r = 0; r < 4; ++r) {
          float h = d1[nt][mt][r] + bb;
          h = 0.5f * h * (1.f + erff(h * 0.70710678118654752f));  // exact GELU
          hid[mt*16 + lg*4 + r][nl] = f2bf(h);
        }
    }
    __syncthreads();   // hid half ready

    // GEMM2-half accumulate (k over this half's 128 hidden)
#pragma unroll
    for (int ks = 0; ks < 4; ++ks) {
      const bf16x8 bw = *(const bf16x8*)&w2t[(g*16 + lr)*256 + half*128 + ks*32 + lg*8];
#pragma unroll
      for (int mt = 0; mt < 4; ++mt) {
        const bf16x8 af = *(const bf16x8*)&hid[mt*16 + lr][ks*32 + lg*8];
        d2[mt] = __builtin_amdgcn_mfma_f32_16x16x32_bf16(af, bw, d2[mt], 0, 0, 0);
      }
    }
    __syncthreads();   // hid consumed; safe to overwrite next half
  }

  // ---- merge FFN into ob ----
  {
    const float b2n = b2[g*16 + lr];
#pragma unroll
    for (int mt = 0; mt < 4; ++mt)
#pragma unroll
      for (int r = 0; r < 4; ++r)
        ob[mt*16 + lg*4 + r][g*16 + lr] += d2[mt][r] + b2n;
  }
  __syncthreads();

  // ---- write out (B,C,H,W) ----
#pragma unroll
  for (int i = 0; i < 16; ++i) {
    const int idx = i * 256 + tid;
    const int c = idx >> 6, t = idx & 63;
    out[(((size_t)b*64 + c)*256 + (y0 + (t >> 3)))*256 + (x0 + (t & 7))] = ob[t][c];
  }
}

extern "C" void kernel_launch(void* const* d_in, const int* in_sizes, int n_in,
                              void* d_out, int out_size, void* d_ws, size_t ws_size,
                              hipStream_t stream) {
  const float* x      = (const float*)d_in[0];
  const float* qkv_w  = (const float*)d_in[1];
  const float* qkv_b  = (const float*)d_in[2];
  const float* proj_w = (const float*)d_in[3];
  const float* proj_b = (const float*)d_in[4];
  const float* rpb    = (const float*)d_in[5];
  const float* n1g    = (const float*)d_in[6];
  const float* n1b    = (const float*)d_in[7];
  const float* n2g    = (const float*)d_in[8];
  const float* n2b    = (const float*)d_in[9];
  const float* w1     = (const float*)d_in[10];
  const float* b1     = (const float*)d_in[11];
  const float* w2     = (const float*)d_in[12];
  const float* b2     = (const float*)d_in[13];
  const float* dww    = (const float*)d_in[14];
  const float* dwb    = (const float*)d_in[15];
  float* out = (float*)d_out;

  // workspace: x1 bf16 (64 MiB) | packed weights (96 KiB)
  unsigned short* x1bf = (unsigned short*)d_ws;
  unsigned short* wbuf = (unsigned short*)((char*)d_ws + 67108864);
  unsigned short* qkvt = wbuf;            // 192*64
  unsigned short* projt= wbuf + 12288;    // 64*64
  unsigned short* w1t  = wbuf + 16384;    // 256*64
  unsigned short* w2t  = wbuf + 32768;    // 64*256

  pack_weights_kernel<<<64, 256, 0, stream>>>(qkv_w, proj_w, w1, w2,
                                              qkvt, projt, w1t, w2t);
  win_attn_kernel<<<8192, 256, 0, stream>>>(x, qkvt, qkv_b, projt, proj_b,
                                            rpb, n1g, n1b, x1bf);
  ffn_conv_kernel<<<8192, 256, 0, stream>>>(x1bf, n2g, n2b, w1t, b1, w2t, b2,
                                            dww, dwb, out);
}

// Round 5
// 334.141 us; speedup vs baseline: 9.5255x; 1.2232x over previous
//
#include <hip/hip_runtime.h>
#include <cmath>

// LeWin block: B=8, C=64, H=W=256, ws=8, heads=4, hd=16, hidden=256.
// Kernel P: pack weights bf16 [n][k] + precompute rel-pos bias table [4][64][64]
// Kernel A: LN1 + window attention (register-resident MFMA chain) -> x1 bf16 (B,H,W,C)
// Kernel B: LN2 + FFN (bf16 MFMA, 2 hidden halves) + depthwise conv + adds -> out (B,C,H,W)

typedef __attribute__((ext_vector_type(8))) short bf16x8;
typedef __attribute__((ext_vector_type(4))) short s16x4;
typedef __attribute__((ext_vector_type(4))) float f32x4;

static __device__ __forceinline__ unsigned short f2bf(float f) {
  union { float f; unsigned u; } v; v.f = f;
  unsigned r = v.u + 0x7FFF + ((v.u >> 16) & 1);   // round-to-nearest-even
  return (unsigned short)(r >> 16);
}
static __device__ __forceinline__ float bf2f(unsigned short u) {
  union { unsigned u; float f; } v; v.u = ((unsigned)u) << 16;
  return v.f;
}
static __device__ __forceinline__ float bf2f_s(short s) { return bf2f((unsigned short)s); }

// granule-XOR swizzled addressing for pitch-72 (shorts) token-major bf16 tiles:
// element (row, c) lives at row*72 + ((c>>3 ^ row>>3)&7)*8 + (c&7).
// Kills the 8-way bank conflict of the 144B-pitch transpose write (4*row mod 32 has period 8).
static __device__ __forceinline__ int swz(int row, int c) {
  return row * 72 + ((((c >> 3) ^ (row >> 3)) & 7) << 3) + (c & 7);
}
static __device__ __forceinline__ int swzg(int row, int g) {
  return row * 72 + (((g ^ (row >> 3)) & 7) << 3);
}

#define MFMA32(a, b, c) __builtin_amdgcn_mfma_f32_16x16x32_bf16(a, b, c, 0, 0, 0)

#if __has_builtin(__builtin_amdgcn_mfma_f32_16x16x16bf16_1k)
static __device__ __forceinline__ f32x4 MFMA16(s16x4 a, s16x4 b, f32x4 c) {
  return __builtin_amdgcn_mfma_f32_16x16x16bf16_1k(a, b, c, 0, 0, 0);
}
#else
// exact emulation: place the 4 k-values in slots lg*8+0..3 of a K=32 mfma and zero the rest;
// A and B use the same k-permutation so the dot product is unchanged.
static __device__ __forceinline__ f32x4 MFMA16(s16x4 a, s16x4 b, f32x4 c) {
  bf16x8 a8 = (bf16x8){a[0], a[1], a[2], a[3], 0, 0, 0, 0};
  bf16x8 b8 = (bf16x8){b[0], b[1], b[2], b[3], 0, 0, 0, 0};
  return __builtin_amdgcn_mfma_f32_16x16x32_bf16(a8, b8, c, 0, 0, 0);
}
#endif

// ==================== Kernel P: weight packing + bias table ====================
// qkvt [192][64], projt [64][64], w1t [256][64], w2t [64][256] (bf16, k-contiguous)
// biasg [4][64][64] f32: biasg[h][i][j] = rpb[ridx(i,j)*4 + h]
__global__ void pack_weights_kernel(const float* __restrict__ qkv_w,
                                    const float* __restrict__ proj_w,
                                    const float* __restrict__ w1,
                                    const float* __restrict__ w2,
                                    const float* __restrict__ rpb,
                                    unsigned short* __restrict__ qkvt,
                                    unsigned short* __restrict__ projt,
                                    unsigned short* __restrict__ w1t,
                                    unsigned short* __restrict__ w2t,
                                    float* __restrict__ biasg) {
  const int t = blockIdx.x * 256 + threadIdx.x;   // 0..16383
  {
    const int n = t >> 6, k = t & 63;
    if (n < 192) qkvt[t] = f2bf(qkv_w[k * 192 + n]);
    if (n < 64)  projt[t] = f2bf(proj_w[k * 64 + n]);
    w1t[t] = f2bf(w1[k * 256 + n]);
  }
  {
    const int n = t >> 8, k = t & 255;
    w2t[t] = f2bf(w2[k * 64 + n]);
  }
  {
    const int i = (t >> 6) & 63, j = t & 63, h = t >> 12;
    const int ridx = ((i >> 3) - (j >> 3) + 7) * 15 + ((i & 7) - (j & 7) + 7);
    biasg[t] = rpb[ridx * 4 + h];
  }
}

// ==================== Kernel A: register-chain MFMA window attention ====================
__global__ __launch_bounds__(256, 3)
void win_attn_kernel(const float* __restrict__ x,
                     const unsigned short* __restrict__ qkvt,
                     const float* __restrict__ qkv_b,
                     const unsigned short* __restrict__ projt,
                     const float* __restrict__ proj_b,
                     const float* __restrict__ biasg,
                     const float* __restrict__ n1g,
                     const float* __restrict__ n1b,
                     unsigned short* __restrict__ x1b)
{
  __shared__ unsigned short xw[64 * 72];   // residual bf16, swizzled
  __shared__ unsigned short xn[64 * 72];   // LN1 bf16 -> oh -> store staging, swizzled

  const int tid = threadIdx.x;
  const int bid = blockIdx.x;
  const int wid = ((bid & 7) << 10) | (bid >> 3);   // XCD-contiguous windows
  const int b  = wid >> 10;
  const int wy = (wid >> 5) & 31;
  const int wx = wid & 31;
  const int y0 = wy << 3, x0 = wx << 3;

  // ---- load + transpose (B,C,H,W) -> xw[token][channel] bf16 ----
  const size_t imgbase = (size_t)b << 22;
#pragma unroll
  for (int i = 0; i < 16; ++i) {
    const int idx = i * 256 + tid;
    const int c = idx >> 6, t = idx & 63;
    const float v = x[imgbase + ((size_t)c << 16) + (size_t)(y0 + (t >> 3)) * 256 + (x0 + (t & 7))];
    xw[swz(t, c)] = f2bf(v);
  }
  __syncthreads();

  // ---- LayerNorm1 (4 lanes per token) -> xn bf16 ----
  {
    const int t = tid >> 2, q = tid & 3;
    const bf16x8 h0 = *(const bf16x8*)&xw[swzg(t, 2 * q)];
    const bf16x8 h1 = *(const bf16x8*)&xw[swzg(t, 2 * q + 1)];
    float xv[16], s = 0.f, s2 = 0.f;
#pragma unroll
    for (int j = 0; j < 8; ++j) { xv[j] = bf2f_s(h0[j]); xv[8 + j] = bf2f_s(h1[j]); }
#pragma unroll
    for (int j = 0; j < 16; ++j) { s += xv[j]; s2 += xv[j] * xv[j]; }
    s  += __shfl_xor(s, 1);  s  += __shfl_xor(s, 2);
    s2 += __shfl_xor(s2, 1); s2 += __shfl_xor(s2, 2);
    const float mu   = s * 0.015625f;
    const float rstd = rsqrtf(s2 * 0.015625f - mu * mu + 1e-5f);
#pragma unroll
    for (int j = 0; j < 8; ++j) {
      const int c = q * 16 + j * 2;
      const float a0 = (xv[j * 2 + 0] - mu) * rstd * n1g[c]     + n1b[c];
      const float a1 = (xv[j * 2 + 1] - mu) * rstd * n1g[c + 1] + n1b[c + 1];
      *(unsigned*)&xn[swz(t, c)] = (unsigned)f2bf(a0) | ((unsigned)f2bf(a1) << 16);
    }
  }
  __syncthreads();

  const int lane = tid & 63;
  const int g    = tid >> 6;       // wave = head
  const int lr   = lane & 15;
  const int lg   = lane >> 4;

  // A-fragments of LN1 output (used as A for V and as B for Q^T/K^T)
  bf16x8 afr[4][2];
#pragma unroll
  for (int mt = 0; mt < 4; ++mt)
#pragma unroll
    for (int ks = 0; ks < 2; ++ks)
      afr[mt][ks] = *(const bf16x8*)&xn[swzg(mt * 16 + lr, ks * 4 + lg)];
  __syncthreads();   // xn dead -> reusable as oh

  // ---- QKV (24 MFMA): Q^T,K^T via swapped operands; V normal ----
  f32x4 dqT[4], dkT[4], dv[4];
#pragma unroll
  for (int u = 0; u < 4; ++u) { dqT[u] = (f32x4){0,0,0,0}; dkT[u] = (f32x4){0,0,0,0}; dv[u] = (f32x4){0,0,0,0}; }
  const int nbq = g * 16, nbk = 64 + g * 16, nbv = 128 + g * 16;
#pragma unroll
  for (int ks = 0; ks < 2; ++ks) {
    const bf16x8 wq = *(const bf16x8*)&qkvt[(nbq + lr) * 64 + ks * 32 + lg * 8];
    const bf16x8 wk = *(const bf16x8*)&qkvt[(nbk + lr) * 64 + ks * 32 + lg * 8];
    const bf16x8 wv = *(const bf16x8*)&qkvt[(nbv + lr) * 64 + ks * 32 + lg * 8];
#pragma unroll
    for (int u = 0; u < 4; ++u) {
      dqT[u] = MFMA32(wq, afr[u][ks], dqT[u]);   // D[d][tok]
      dkT[u] = MFMA32(wk, afr[u][ks], dkT[u]);   // D[d][tok]
      dv[u]  = MFMA32(afr[u][ks], wv, dv[u]);    // D[tok][d]
    }
  }
  // biases -> bf16 fragments (layouts chain exactly into the K=16 MFMAs)
  s16x4 qf[4], kf[4], vf[4];
  {
    const float4 qb = *(const float4*)&qkv_b[nbq + lg * 4];
    const float4 kb = *(const float4*)&qkv_b[nbk + lg * 4];
    const float  vb = qkv_b[nbv + lr];
#pragma unroll
    for (int u = 0; u < 4; ++u) {
      qf[u] = (s16x4){(short)f2bf((dqT[u][0] + qb.x) * 0.25f), (short)f2bf((dqT[u][1] + qb.y) * 0.25f),
                      (short)f2bf((dqT[u][2] + qb.z) * 0.25f), (short)f2bf((dqT[u][3] + qb.w) * 0.25f)};
      kf[u] = (s16x4){(short)f2bf(dkT[u][0] + kb.x), (short)f2bf(dkT[u][1] + kb.y),
                      (short)f2bf(dkT[u][2] + kb.z), (short)f2bf(dkT[u][3] + kb.w)};
      vf[u] = (s16x4){(short)f2bf(dv[u][0] + vb), (short)f2bf(dv[u][1] + vb),
                      (short)f2bf(dv[u][2] + vb), (short)f2bf(dv[u][3] + vb)};
    }
  }

  // ---- S^T = K @ Q^T (16 K=16-MFMA) + bias + softmax, all in registers ----
  f32x4 sacc[4][4];
#pragma unroll
  for (int mt = 0; mt < 4; ++mt)
#pragma unroll
    for (int nt = 0; nt < 4; ++nt) {
      f32x4 z = (f32x4){0,0,0,0};
      sacc[mt][nt] = MFMA16(kf[mt], qf[nt], z);   // lane: S[i=nt*16+lr][j=mt*16+lg*4+r]
    }
#pragma unroll
  for (int nt = 0; nt < 4; ++nt)
#pragma unroll
    for (int mt = 0; mt < 4; ++mt) {
      const float4 bb = *(const float4*)&biasg[(g << 12) + (nt * 16 + lr) * 64 + mt * 16 + lg * 4];
      sacc[mt][nt][0] += bb.x; sacc[mt][nt][1] += bb.y;
      sacc[mt][nt][2] += bb.z; sacc[mt][nt][3] += bb.w;
    }

  s16x4 pa[4][4];   // P as PV A-fragments
#pragma unroll
  for (int nt = 0; nt < 4; ++nt) {
    float mx = -1e30f;
#pragma unroll
    for (int mt = 0; mt < 4; ++mt)
#pragma unroll
      for (int r = 0; r < 4; ++r) mx = fmaxf(mx, sacc[mt][nt][r]);
    mx = fmaxf(mx, __shfl_xor(mx, 16));
    mx = fmaxf(mx, __shfl_xor(mx, 32));
    float sum = 0.f;
#pragma unroll
    for (int mt = 0; mt < 4; ++mt)
#pragma unroll
      for (int r = 0; r < 4; ++r) { const float e = __expf(sacc[mt][nt][r] - mx); sacc[mt][nt][r] = e; sum += e; }
    sum += __shfl_xor(sum, 16);
    sum += __shfl_xor(sum, 32);
    const float rs = 1.f / sum;
#pragma unroll
    for (int mt = 0; mt < 4; ++mt)
      pa[mt][nt] = (s16x4){(short)f2bf(sacc[mt][nt][0] * rs), (short)f2bf(sacc[mt][nt][1] * rs),
                           (short)f2bf(sacc[mt][nt][2] * rs), (short)f2bf(sacc[mt][nt][3] * rs)};
  }

  // ---- O = P @ V (16 K=16-MFMA) ----
  f32x4 o[4];
#pragma unroll
  for (int nt = 0; nt < 4; ++nt) {
    o[nt] = (f32x4){0,0,0,0};
#pragma unroll
    for (int mt = 0; mt < 4; ++mt)
      o[nt] = MFMA16(pa[mt][nt], vf[mt], o[nt]);   // lane: O[i=nt*16+lg*4+r][d=lr]
  }

  // ---- oh (reuses xn) ----
#pragma unroll
  for (int nt = 0; nt < 4; ++nt)
#pragma unroll
    for (int r = 0; r < 4; ++r)
      xn[swz(nt * 16 + lg * 4 + r, g * 16 + lr)] = f2bf(o[nt][r]);
  __syncthreads();

  // ---- proj (8 MFMA) + bias + residual -> staging -> coalesced bf16 store ----
  {
    bf16x8 pa2[4][2];
#pragma unroll
    for (int mt = 0; mt < 4; ++mt)
#pragma unroll
      for (int ks = 0; ks < 2; ++ks)
        pa2[mt][ks] = *(const bf16x8*)&xn[swzg(mt * 16 + lr, ks * 4 + lg)];
    __syncthreads();   // oh reads done; xn free for staging

    f32x4 d2[4];
#pragma unroll
    for (int mt = 0; mt < 4; ++mt) d2[mt] = (f32x4){0,0,0,0};
#pragma unroll
    for (int ks = 0; ks < 2; ++ks) {
      const bf16x8 pb = *(const bf16x8*)&projt[(g * 16 + lr) * 64 + ks * 32 + lg * 8];
#pragma unroll
      for (int mt = 0; mt < 4; ++mt)
        d2[mt] = MFMA32(pa2[mt][ks], pb, d2[mt]);
    }
    const float pbias = proj_b[g * 16 + lr];
#pragma unroll
    for (int mt = 0; mt < 4; ++mt)
#pragma unroll
      for (int r = 0; r < 4; ++r) {
        const int tok = mt * 16 + lg * 4 + r;
        const float val = d2[mt][r] + pbias + bf2f(xw[swz(tok, g * 16 + lr)]);
        xn[swz(tok, g * 16 + lr)] = f2bf(val);
      }
  }
  __syncthreads();

#pragma unroll
  for (int i = 0; i < 2; ++i) {
    const int u = i * 256 + tid;              // 512 bf16x8 units
    const int tok = u >> 3, gr = u & 7;
    const bf16x8 v = *(const bf16x8*)&xn[swzg(tok, gr)];
    *(bf16x8*)&x1b[(((size_t)b * 256 + y0 + (tok >> 3)) * 256 + x0 + (tok & 7)) * 64 + gr * 8] = v;
  }
}

// ==================== Kernel B: LN2 + MFMA FFN (2 halves) + dwconv ====================
__global__ __launch_bounds__(256, 4)
void ffn_conv_kernel(const unsigned short* __restrict__ x1b,
                     const float* __restrict__ n2g, const float* __restrict__ n2b,
                     const unsigned short* __restrict__ w1t, const float* __restrict__ b1,
                     const unsigned short* __restrict__ w2t, const float* __restrict__ b2,
                     const float* __restrict__ dww, const float* __restrict__ dwb,
                     float* __restrict__ out)
{
  // pool: x1h [100][72] (7200 sh) | xn [64][72] (4608 sh, swizzled); hid [64][136] (8704 sh) overlays
  __shared__ unsigned short pool[11808];     // 23616 B
  __shared__ float          ob[64][65];      // 16640 B; total 40256 B -> 4 blocks/CU
  unsigned short* x1h = pool;
  unsigned short* xnb = pool + 7200;
  unsigned short* hid = pool;

  const int tid = threadIdx.x;
  const int bid = blockIdx.x;
  const int wid = ((bid & 7) << 10) | (bid >> 3);
  const int b  = wid >> 10;
  const int wy = (wid >> 5) & 31;
  const int wx = wid & 31;
  const int y0 = wy << 3, x0 = wx << 3;

  // ---- halo load (100 px x 64 ch bf16) ----
#pragma unroll
  for (int i = 0; i < 7; ++i) {
    const int u = i * 256 + tid;               // 1600 uint2 units
    if (u < 1600) {
      const int p = u >> 4, c4 = (u & 15) << 2;
      const int py = p / 10, px = p - py * 10;
      const int gy = y0 + py - 1, gx = x0 + px - 1;
      uint2 v = make_uint2(0u, 0u);
      if ((unsigned)gy < 256u && (unsigned)gx < 256u)
        v = *(const uint2*)&x1b[(((size_t)b * 256 + gy) * 256 + gx) * 64 + c4];
      *(uint2*)&x1h[p * 72 + c4] = v;
    }
  }
  __syncthreads();

  const int lane = tid & 63;
  const int g    = tid >> 6;
  const int lr   = lane & 15;
  const int lg   = lane >> 4;

  // ---- LayerNorm2 (4 lanes per token) from halo interior -> xnb bf16 (swizzled) ----
  {
    const int t = tid >> 2, q = tid & 3;
    const int pp = ((t >> 3) + 1) * 10 + (t & 7) + 1;
    const bf16x8 h0 = *(const bf16x8*)&x1h[pp * 72 + q * 16];
    const bf16x8 h1 = *(const bf16x8*)&x1h[pp * 72 + q * 16 + 8];
    float xv[16], s = 0.f, s2 = 0.f;
#pragma unroll
    for (int j = 0; j < 8; ++j) { xv[j] = bf2f_s(h0[j]); xv[8 + j] = bf2f_s(h1[j]); }
#pragma unroll
    for (int j = 0; j < 16; ++j) { s += xv[j]; s2 += xv[j] * xv[j]; }
    s  += __shfl_xor(s, 1);  s  += __shfl_xor(s, 2);
    s2 += __shfl_xor(s2, 1); s2 += __shfl_xor(s2, 2);
    const float mu   = s * 0.015625f;
    const float rstd = rsqrtf(s2 * 0.015625f - mu * mu + 1e-5f);
#pragma unroll
    for (int j = 0; j < 8; ++j) {
      const int c = q * 16 + j * 2;
      const float a0 = (xv[j * 2 + 0] - mu) * rstd * n2g[c]     + n2b[c];
      const float a1 = (xv[j * 2 + 1] - mu) * rstd * n2g[c + 1] + n2b[c + 1];
      *(unsigned*)&xnb[swz(t, c)] = (unsigned)f2bf(a0) | ((unsigned)f2bf(a1) << 16);
    }
  }

  // ---- depthwise conv + residual -> ob ----
  {
    const int cty = lane >> 3, ctx = lane & 7;
    float cacc[16];
#pragma unroll
    for (int i = 0; i < 16; ++i) cacc[i] = dwb[g * 16 + i];
#pragma unroll
    for (int dy = 0; dy < 3; ++dy)
#pragma unroll
      for (int dx = 0; dx < 3; ++dx) {
        const int p = (cty + dy) * 10 + (ctx + dx);
        const bf16x8 h0 = *(const bf16x8*)&x1h[p * 72 + g * 16];
        const bf16x8 h1 = *(const bf16x8*)&x1h[p * 72 + g * 16 + 8];
#pragma unroll
        for (int i = 0; i < 8; ++i) {
          cacc[i]     += dww[(g * 16 + i) * 9     + dy * 3 + dx] * bf2f_s(h0[i]);
          cacc[8 + i] += dww[(g * 16 + 8 + i) * 9 + dy * 3 + dx] * bf2f_s(h1[i]);
        }
      }
    const int cp = (cty + 1) * 10 + (ctx + 1);
    const bf16x8 r0 = *(const bf16x8*)&x1h[cp * 72 + g * 16];
    const bf16x8 r1 = *(const bf16x8*)&x1h[cp * 72 + g * 16 + 8];
#pragma unroll
    for (int i = 0; i < 8; ++i) {
      ob[lane][g * 16 + i]     = bf2f_s(r0[i]) + cacc[i];
      ob[lane][g * 16 + 8 + i] = bf2f_s(r1[i]) + cacc[8 + i];
    }
  }
  __syncthreads();   // xnb ready; all x1h reads done

  bf16x8 afr[4][2];
#pragma unroll
  for (int mt = 0; mt < 4; ++mt)
#pragma unroll
    for (int ks = 0; ks < 2; ++ks)
      afr[mt][ks] = *(const bf16x8*)&xnb[swzg(mt * 16 + lr, ks * 4 + lg)];
  __syncthreads();   // afr loaded -> pool reusable as hid

  f32x4 d2[4];
#pragma unroll
  for (int mt = 0; mt < 4; ++mt) d2[mt] = (f32x4){0,0,0,0};

#pragma unroll
  for (int half = 0; half < 2; ++half) {
    f32x4 d1[2][4];
#pragma unroll
    for (int nt = 0; nt < 2; ++nt)
#pragma unroll
      for (int mt = 0; mt < 4; ++mt) d1[nt][mt] = (f32x4){0,0,0,0};
#pragma unroll
    for (int nt = 0; nt < 2; ++nt) {
      const int n = half * 128 + g * 32 + nt * 16 + lr;
#pragma unroll
      for (int ks = 0; ks < 2; ++ks) {
        const bf16x8 bw = *(const bf16x8*)&w1t[n * 64 + ks * 32 + lg * 8];
#pragma unroll
        for (int mt = 0; mt < 4; ++mt)
          d1[nt][mt] = MFMA32(afr[mt][ks], bw, d1[nt][mt]);
      }
    }
#pragma unroll
    for (int nt = 0; nt < 2; ++nt) {
      const int n  = half * 128 + g * 32 + nt * 16 + lr;
      const int nl = g * 32 + nt * 16 + lr;
      const float bb = b1[n];
#pragma unroll
      for (int mt = 0; mt < 4; ++mt)
#pragma unroll
        for (int r = 0; r < 4; ++r) {
          float h = d1[nt][mt][r] + bb;
          const float z = h * (1.5957691216f + 0.0713548162f * h * h);   // tanh-GELU
          h = h / (1.f + __expf(-z));
          hid[(mt * 16 + lg * 4 + r) * 136 + nl] = f2bf(h);
        }
    }
    __syncthreads();   // hid half ready

#pragma unroll
    for (int ks = 0; ks < 4; ++ks) {
      const bf16x8 bw = *(const bf16x8*)&w2t[(g * 16 + lr) * 256 + half * 128 + ks * 32 + lg * 8];
#pragma unroll
      for (int mt = 0; mt < 4; ++mt) {
        const bf16x8 af = *(const bf16x8*)&hid[(mt * 16 + lr) * 136 + ks * 32 + lg * 8];
        d2[mt] = MFMA32(af, bw, d2[mt]);
      }
    }
    __syncthreads();   // hid consumed
  }

  // ---- merge FFN into ob ----
  {
    const float b2n = b2[g * 16 + lr];
#pragma unroll
    for (int mt = 0; mt < 4; ++mt)
#pragma unroll
      for (int r = 0; r < 4; ++r)
        ob[mt * 16 + lg * 4 + r][g * 16 + lr] += d2[mt][r] + b2n;
  }
  __syncthreads();

  // ---- write out (B,C,H,W) ----
#pragma unroll
  for (int i = 0; i < 16; ++i) {
    const int idx = i * 256 + tid;
    const int c = idx >> 6, t = idx & 63;
    out[(((size_t)b * 64 + c) * 256 + (y0 + (t >> 3))) * 256 + (x0 + (t & 7))] = ob[t][c];
  }
}

extern "C" void kernel_launch(void* const* d_in, const int* in_sizes, int n_in,
                              void* d_out, int out_size, void* d_ws, size_t ws_size,
                              hipStream_t stream) {
  const float* x      = (const float*)d_in[0];
  const float* qkv_w  = (const float*)d_in[1];
  const float* qkv_b  = (const float*)d_in[2];
  const float* proj_w = (const float*)d_in[3];
  const float* proj_b = (const float*)d_in[4];
  const float* rpb    = (const float*)d_in[5];
  const float* n1g    = (const float*)d_in[6];
  const float* n1b    = (const float*)d_in[7];
  const float* n2g    = (const float*)d_in[8];
  const float* n2b    = (const float*)d_in[9];
  const float* w1     = (const float*)d_in[10];
  const float* b1     = (const float*)d_in[11];
  const float* w2     = (const float*)d_in[12];
  const float* b2     = (const float*)d_in[13];
  const float* dww    = (const float*)d_in[14];
  const float* dwb    = (const float*)d_in[15];
  float* out = (float*)d_out;

  // workspace: x1 bf16 (64 MiB) | packed weights (96 KiB) | bias table (64 KiB)
  unsigned short* x1bf = (unsigned short*)d_ws;
  unsigned short* wbuf = (unsigned short*)((char*)d_ws + 67108864);
  unsigned short* qkvt  = wbuf;            // 192*64
  unsigned short* projt = wbuf + 12288;    // 64*64
  unsigned short* w1t   = wbuf + 16384;    // 256*64
  unsigned short* w2t   = wbuf + 32768;    // 64*256
  float* biasg = (float*)((char*)d_ws + 67108864 + 98304);   // 4*64*64

  pack_weights_kernel<<<64, 256, 0, stream>>>(qkv_w, proj_w, w1, w2, rpb,
                                              qkvt, projt, w1t, w2t, biasg);
  win_attn_kernel<<<8192, 256, 0, stream>>>(x, qkvt, qkv_b, projt, proj_b,
                                            biasg, n1g, n1b, x1bf);
  ffn_conv_kernel<<<8192, 256, 0, stream>>>(x1bf, n2g, n2b, w1t, b1, w2t, b2,
                                            dww, dwb, out);
}